// Round 11
// baseline (499.263 us; speedup 1.0000x reference)
//
#include <hip/hip_runtime.h>

#define N_NODES 50000
#define M_PAD   50048            // 391 * 128
#define NBLK    196              // ceil(N_NODES/256)
#define E_EDGES 800000
#define E_TOT   (E_EDGES + N_NODES)
#define IN_C 512
#define HID 256
#define HEADS 8
#define OUT_C 64

typedef unsigned int uint;
typedef unsigned short ushort_t;
typedef __bf16 bf16x8 __attribute__((ext_vector_type(8)));
typedef float f32x4 __attribute__((ext_vector_type(4)));
typedef float f32x2 __attribute__((ext_vector_type(2)));

__device__ __forceinline__ float lrelu(float x) { return x > 0.f ? x : 0.2f * x; }

__device__ __forceinline__ unsigned short f2bf(float f) {
  uint u = __float_as_uint(f);
  u += 0x7FFF + ((u >> 16) & 1);          // RNE
  return (unsigned short)(u >> 16);
}
__device__ __forceinline__ float bflo(uint u) { return __uint_as_float(u << 16); }
__device__ __forceinline__ float bfhi(uint u) { return __uint_as_float(u & 0xFFFF0000u); }
__device__ __forceinline__ float bf2f(ushort_t u) { return __uint_as_float(((uint)u) << 16); }
__device__ __forceinline__ f32x2 unp2(uint u) {
  f32x2 r; r.x = bflo(u); r.y = bfhi(u); return r;
}

// ---------------- CSR build ----------------
__global__ void k_count(const int* __restrict__ ei, int* __restrict__ counts) {
  int e = blockIdx.x * blockDim.x + threadIdx.x;
  if (e >= E_TOT) return;
  int d = (e < E_EDGES) ? ei[E_EDGES + e] : (e - E_EDGES);
  atomicAdd(&counts[d], 1);
}

__global__ void k_bsum(const int* __restrict__ counts, int* __restrict__ bsum) {
  int i = blockIdx.x * 256 + threadIdx.x;
  int v = (i < N_NODES) ? counts[i] : 0;
  __shared__ int ws[4];
  int lane = threadIdx.x & 63, wid = threadIdx.x >> 6;
  #pragma unroll
  for (int off = 32; off; off >>= 1) v += __shfl_xor(v, off);
  if (lane == 0) ws[wid] = v;
  __syncthreads();
  if (threadIdx.x == 0) bsum[blockIdx.x] = ws[0] + ws[1] + ws[2] + ws[3];
}

__global__ void k_bscan(const int* __restrict__ bsum, int* __restrict__ boff) {
  int tid = threadIdx.x;
  int v = (tid < NBLK) ? bsum[tid] : 0;
  int lane = tid & 63, wid = tid >> 6;
  int x = v;
  #pragma unroll
  for (int off = 1; off < 64; off <<= 1) {
    int t = __shfl_up(x, off);
    if (lane >= off) x += t;
  }
  __shared__ int ws[4];
  if (lane == 63) ws[wid] = x;
  __syncthreads();
  int woff = 0;
  for (int w = 0; w < wid; w++) woff += ws[w];
  if (tid < NBLK) boff[tid] = x + woff - v;   // exclusive
}

__global__ void k_local(const int* __restrict__ counts, const int* __restrict__ boff,
                        int* __restrict__ indptr, int* __restrict__ wptr) {
  int b = blockIdx.x;
  int i = b * 256 + threadIdx.x;
  int v = (i < N_NODES) ? counts[i] : 0;
  int lane = threadIdx.x & 63, wid = threadIdx.x >> 6;
  int x = v;
  #pragma unroll
  for (int off = 1; off < 64; off <<= 1) {
    int t = __shfl_up(x, off);
    if (lane >= off) x += t;
  }
  __shared__ int ws[4];
  if (lane == 63) ws[wid] = x;
  __syncthreads();
  int woff = boff[b];
  for (int w = 0; w < wid; w++) woff += ws[w];
  int excl = woff + x - v;
  if (i < N_NODES) { indptr[i] = excl; wptr[i] = excl; }
  if (b == 0 && threadIdx.x == 0) indptr[N_NODES] = E_TOT;
}

__global__ void k_scatter(const int* __restrict__ ei, int* __restrict__ wptr,
                          int* __restrict__ csr_src) {
  int e = blockIdx.x * blockDim.x + threadIdx.x;
  if (e >= E_TOT) return;
  int s, d;
  if (e < E_EDGES) { s = ei[e]; d = ei[E_EDGES + e]; }
  else { s = d = e - E_EDGES; }
  int pos = atomicAdd(&wptr[d], 1);
  csr_src[pos] = s;
}

// ---------------- weight transposes (tiny) ----------------
__global__ void k_conv_w1(const float* __restrict__ W1, ushort_t* __restrict__ w1t) {
  int t = blockIdx.x * blockDim.x + threadIdx.x;
  if (t >= HID * IN_C) return;
  int n = t >> 9, k = t & 511;
  w1t[t] = f2bf(W1[(size_t)k * HID + n]);
}
__global__ void k_conv_w2(const float* __restrict__ W2, ushort_t* __restrict__ w2t) {
  int t = blockIdx.x * blockDim.x + threadIdx.x;
  if (t >= OUT_C * HID) return;
  int n = t >> 8, k = t & 255;
  w2t[t] = f2bf(W2[(size_t)k * OUT_C + n]);
}

// ---------------- GEMM1: h1b = bf16(x @ W1) ----------------
__global__ __launch_bounds__(512) void k_mm1(const float* __restrict__ A,
                                             const ushort_t* __restrict__ Bt,
                                             ushort_t* __restrict__ Cb) {
  __shared__ ushort_t sA[128][40];
  __shared__ ushort_t sB[256][40];
  int tid = threadIdx.x;
  int wid = tid >> 6, lane = tid & 63;
  int wm = wid >> 2, wn = wid & 3;
  int lr = lane & 15, kg = lane >> 4;
  int row0 = blockIdx.x * 128;
  f32x4 acc[4][4] = {};

  for (int k0 = 0; k0 < IN_C; k0 += 32) {
    {
      int r = tid >> 2, cs = (tid & 3) * 8;
      int gr = row0 + r;
      unsigned short v[8];
      if (gr < N_NODES) {
        const float* src = A + (size_t)gr * IN_C + k0 + cs;
        float4 f0 = *reinterpret_cast<const float4*>(src);
        float4 f1 = *reinterpret_cast<const float4*>(src + 4);
        v[0] = f2bf(f0.x); v[1] = f2bf(f0.y); v[2] = f2bf(f0.z); v[3] = f2bf(f0.w);
        v[4] = f2bf(f1.x); v[5] = f2bf(f1.y); v[6] = f2bf(f1.z); v[7] = f2bf(f1.w);
      } else {
        #pragma unroll
        for (int i = 0; i < 8; i++) v[i] = 0;
      }
      uint4 pk;
      pk.x = v[0] | ((uint)v[1] << 16); pk.y = v[2] | ((uint)v[3] << 16);
      pk.z = v[4] | ((uint)v[5] << 16); pk.w = v[6] | ((uint)v[7] << 16);
      *reinterpret_cast<uint4*>(&sA[r][cs]) = pk;
    }
    {
      int n = tid >> 1, ks = (tid & 1) * 16;
      const ushort_t* src = Bt + (size_t)n * IN_C + k0 + ks;
      uint4 v0 = *reinterpret_cast<const uint4*>(src);
      uint4 v1 = *reinterpret_cast<const uint4*>(src + 8);
      *reinterpret_cast<uint4*>(&sB[n][ks]) = v0;
      *reinterpret_cast<uint4*>(&sB[n][ks + 8]) = v1;
    }
    __syncthreads();

    bf16x8 af[4], bfr[4];
    #pragma unroll
    for (int i = 0; i < 4; i++)
      af[i] = *reinterpret_cast<const bf16x8*>(&sA[wm * 64 + i * 16 + lr][kg * 8]);
    #pragma unroll
    for (int j = 0; j < 4; j++)
      bfr[j] = *reinterpret_cast<const bf16x8*>(&sB[wn * 64 + j * 16 + lr][kg * 8]);
    #pragma unroll
    for (int i = 0; i < 4; i++)
      #pragma unroll
      for (int j = 0; j < 4; j++)
        acc[i][j] = __builtin_amdgcn_mfma_f32_16x16x32_bf16(af[i], bfr[j], acc[i][j], 0, 0, 0);
    __syncthreads();
  }

  #pragma unroll
  for (int i = 0; i < 4; i++) {
    #pragma unroll
    for (int j = 0; j < 4; j++) {
      int gc = wn * 64 + j * 16 + lr;
      #pragma unroll
      for (int q = 0; q < 4; q++) {
        int gr = row0 + wm * 64 + i * 16 + kg * 4 + q;
        if (gr < N_NODES) Cb[(size_t)gr * HID + gc] = f2bf(acc[i][j][q]);
      }
    }
  }
}

// ---------------- GEMM2: h2b = bf16(hpb_tiled @ W2) ----------------
__global__ __launch_bounds__(256) void k_mm2(const ushort_t* __restrict__ At,
                                             const ushort_t* __restrict__ Bt,
                                             ushort_t* __restrict__ Cb) {
  __shared__ ushort_t sA[128][40];
  __shared__ ushort_t sB[64][40];
  int tid = threadIdx.x;
  int wid = tid >> 6, lane = tid & 63;
  int lr = lane & 15, kg = lane >> 4;
  int row0 = blockIdx.x * 128;
  f32x4 acc[2][4] = {};

  for (int kt = 0; kt < HID / 32; ++kt) {
    {
      const ushort_t* src = At + ((size_t)blockIdx.x * 8 + kt) * 4096 + tid * 16;
      uint4 v0 = *reinterpret_cast<const uint4*>(src);
      uint4 v1 = *reinterpret_cast<const uint4*>(src + 8);
      int r = tid >> 1, ks = (tid & 1) * 16;
      *reinterpret_cast<uint4*>(&sA[r][ks]) = v0;
      *reinterpret_cast<uint4*>(&sA[r][ks + 8]) = v1;
    }
    if (tid < 128) {
      int n = tid >> 1, ks = (tid & 1) * 16;
      const ushort_t* src = Bt + (size_t)n * HID + kt * 32 + ks;
      uint4 v0 = *reinterpret_cast<const uint4*>(src);
      uint4 v1 = *reinterpret_cast<const uint4*>(src + 8);
      *reinterpret_cast<uint4*>(&sB[n][ks]) = v0;
      *reinterpret_cast<uint4*>(&sB[n][ks + 8]) = v1;
    }
    __syncthreads();

    bf16x8 af[2], bfr[4];
    #pragma unroll
    for (int i = 0; i < 2; i++)
      af[i] = *reinterpret_cast<const bf16x8*>(&sA[wid * 32 + i * 16 + lr][kg * 8]);
    #pragma unroll
    for (int j = 0; j < 4; j++)
      bfr[j] = *reinterpret_cast<const bf16x8*>(&sB[j * 16 + lr][kg * 8]);
    #pragma unroll
    for (int i = 0; i < 2; i++)
      #pragma unroll
      for (int j = 0; j < 4; j++)
        acc[i][j] = __builtin_amdgcn_mfma_f32_16x16x32_bf16(af[i], bfr[j], acc[i][j], 0, 0, 0);
    __syncthreads();
  }

  #pragma unroll
  for (int i = 0; i < 2; i++) {
    #pragma unroll
    for (int j = 0; j < 4; j++) {
      int gc = j * 16 + lr;
      #pragma unroll
      for (int q = 0; q < 4; q++) {
        int gr = row0 + wid * 32 + i * 16 + kg * 4 + q;
        if (gr < N_NODES) Cb[(size_t)gr * OUT_C + gc] = f2bf(acc[i][j][q]);
      }
    }
  }
}

// ---------------- attention logits (planar as1p/ad1p: [h][n]) ----------------
__global__ void k_alpha1(const ushort_t* __restrict__ h1b, const float* __restrict__ a_src,
                         const float* __restrict__ a_dst, float* __restrict__ as1p,
                         float* __restrict__ ad1p) {
  int t = blockIdx.x * blockDim.x + threadIdx.x;
  if (t >= N_NODES * HEADS) return;
  int n = t >> 3, h = t & 7;
  const ushort_t* row = h1b + (size_t)n * HID + h * 32;
  const float* asr = a_src + h * 32;
  const float* adr = a_dst + h * 32;
  float ss = 0.f, sd = 0.f;
  #pragma unroll
  for (int c = 0; c < 32; c += 8) {
    uint4 rv = *reinterpret_cast<const uint4*>(row + c);
    uint uu[4] = {rv.x, rv.y, rv.z, rv.w};
    #pragma unroll
    for (int q = 0; q < 4; q++) {
      float f0 = bflo(uu[q]), f1 = bfhi(uu[q]);
      ss += f0 * asr[c + q * 2] + f1 * asr[c + q * 2 + 1];
      sd += f0 * adr[c + q * 2] + f1 * adr[c + q * 2 + 1];
    }
  }
  as1p[(size_t)h * N_NODES + n] = ss;
  ad1p[(size_t)h * N_NODES + n] = sd;
}

__global__ void k_alpha2(const ushort_t* __restrict__ h2b, const float* __restrict__ a_src,
                         const float* __restrict__ a_dst, float* __restrict__ as2,
                         float* __restrict__ ad2) {
  int wave = threadIdx.x >> 6, lane = threadIdx.x & 63;
  int n = blockIdx.x * 4 + wave;
  if (n >= N_NODES) return;
  float v = bf2f(h2b[(size_t)n * OUT_C + lane]);
  float ss = v * a_src[lane];
  float sd = v * a_dst[lane];
  #pragma unroll
  for (int off = 32; off; off >>= 1) {
    ss += __shfl_xor(ss, off);
    sd += __shfl_xor(sd, off);
  }
  if (lane == 0) { as2[n] = ss; ad2[n] = sd; }
}

// ---------------- layer-1 aggregation: per-head slice (64B line/node), XCD-pinned ----------------
// grid = 12500 chunks * 8 slots; slot = bid&7 = head -> XCD (bid%8 round-robin);
// node = (bid>>3)*4 + wave. Per (node, head): 16 edges in parallel (eslot=lane>>2),
// 4 lanes/edge x 16B = one 64B line per edge. Per-XCD resident: 3.2MB slice + 0.6MB aux.
__global__ __launch_bounds__(256) void k_agg1(const ushort_t* __restrict__ h1b,
                                              const int* __restrict__ indptr,
                                              const int* __restrict__ csr_src,
                                              const float* __restrict__ as1p,
                                              const float* __restrict__ ad1p,
                                              const float* __restrict__ b1,
                                              ushort_t* __restrict__ hpb) {
  int slot = blockIdx.x & 7;
  int wave = threadIdx.x >> 6, lane = threadIdx.x & 63;
  int node = (blockIdx.x >> 3) * 4 + wave;        // 12500*4 == 50000 exact
  int beg = indptr[node], end = indptr[node + 1];
  int eslot = lane >> 2, cl = lane & 3;
  float adst = ad1p[(size_t)slot * N_NODES + node];
  const float* asl = as1p + (size_t)slot * N_NODES;
  const ushort_t* hq = h1b + slot * 32 + cl * 8;  // this lane's 16B within the head's 64B

  f32x2 a0 = {0.f, 0.f}, a1 = {0.f, 0.f}, a2 = {0.f, 0.f}, a3 = {0.f, 0.f};
  float dsum = 0.f;
  int e = beg + eslot;
  for (; e + 16 < end; e += 32) {                 // edges e and e+16: 32 gathers in flight/wave
    int s0 = __builtin_nontemporal_load(&csr_src[e]);
    int s1 = __builtin_nontemporal_load(&csr_src[e + 16]);
    float l0 = asl[s0];
    float l1 = asl[s1];
    uint4 r0 = *reinterpret_cast<const uint4*>(&hq[(size_t)s0 * HID]);
    uint4 r1 = *reinterpret_cast<const uint4*>(&hq[(size_t)s1 * HID]);
    float w0 = __expf(lrelu(l0 + adst));
    float w1 = __expf(lrelu(l1 + adst));
    a0 += w0 * unp2(r0.x); a1 += w0 * unp2(r0.y); a2 += w0 * unp2(r0.z); a3 += w0 * unp2(r0.w);
    a0 += w1 * unp2(r1.x); a1 += w1 * unp2(r1.y); a2 += w1 * unp2(r1.z); a3 += w1 * unp2(r1.w);
    dsum += w0 + w1;
  }
  for (; e < end; e += 16) {
    int s = __builtin_nontemporal_load(&csr_src[e]);
    float w = __expf(lrelu(asl[s] + adst));
    uint4 rv = *reinterpret_cast<const uint4*>(&hq[(size_t)s * HID]);
    a0 += w * unp2(rv.x); a1 += w * unp2(rv.y); a2 += w * unp2(rv.z); a3 += w * unp2(rv.w);
    dsum += w;
  }
  // reduce across 16 edge-slots (lane bits 2..5)
  #pragma unroll
  for (int off = 4; off <= 32; off <<= 1) {
    a0.x += __shfl_xor(a0.x, off); a0.y += __shfl_xor(a0.y, off);
    a1.x += __shfl_xor(a1.x, off); a1.y += __shfl_xor(a1.y, off);
    a2.x += __shfl_xor(a2.x, off); a2.y += __shfl_xor(a2.y, off);
    a3.x += __shfl_xor(a3.x, off); a3.y += __shfl_xor(a3.y, off);
    dsum += __shfl_xor(dsum, off);
  }
  float inv = 1.f / (dsum + 1e-16f);

  if (eslot == 0) {                               // lanes 0..3 write 8 ch each = 32 ch
    float acc[8] = {a0.x, a0.y, a1.x, a1.y, a2.x, a2.y, a3.x, a3.y};
    int c0 = slot * 32 + cl * 8;
    unsigned short ob[8];
    #pragma unroll
    for (int j = 0; j < 8; j++) {
      float o = acc[j] * inv + b1[c0 + j];
      o = o > 0.f ? o : expm1f(o);
      ob[j] = f2bf(o);
    }
    uint4 pk;
    pk.x = ob[0] | ((uint)ob[1] << 16); pk.y = ob[2] | ((uint)ob[3] << 16);
    pk.z = ob[4] | ((uint)ob[5] << 16); pk.w = ob[6] | ((uint)ob[7] << 16);
    size_t addr = ((size_t)(node >> 7) * 8 + slot) * 4096 + (size_t)(node & 127) * 32 + cl * 8;
    *reinterpret_cast<uint4*>(&hpb[addr]) = pk;
  }
}

// ---------------- layer-2 aggregation: bf16 gather, unroll-4 (R8 structure) ----------------
__global__ __launch_bounds__(256) void k_agg2(const ushort_t* __restrict__ h2b,
                                              const int* __restrict__ indptr,
                                              const int* __restrict__ csr_src,
                                              const float* __restrict__ as2,
                                              const float* __restrict__ ad2,
                                              const float* __restrict__ b2,
                                              float* __restrict__ out) {
  int wave = threadIdx.x >> 6, lane = threadIdx.x & 63;
  int node = blockIdx.x * 4 + wave;
  if (node >= N_NODES) return;
  int beg = indptr[node], end = indptr[node + 1];
  int half = lane >> 5, sl = lane & 31;   // lane sl covers ch 2sl, 2sl+1 (4B bf16x2)
  float adst = ad2[node];

  f32x2 acc2 = {0.f, 0.f};
  float dsum = 0.f;
  int e = beg + half;
  for (; e + 6 < end; e += 8) {
    int s0 = csr_src[e];
    int s1 = csr_src[e + 2];
    int s2 = csr_src[e + 4];
    int s3 = csr_src[e + 6];
    float l0 = as2[s0];
    float l1 = as2[s1];
    float l2 = as2[s2];
    float l3 = as2[s3];
    uint v0 = *reinterpret_cast<const uint*>(&h2b[(size_t)s0 * OUT_C + sl * 2]);
    uint v1 = *reinterpret_cast<const uint*>(&h2b[(size_t)s1 * OUT_C + sl * 2]);
    uint v2 = *reinterpret_cast<const uint*>(&h2b[(size_t)s2 * OUT_C + sl * 2]);
    uint v3 = *reinterpret_cast<const uint*>(&h2b[(size_t)s3 * OUT_C + sl * 2]);
    float w0 = __expf(lrelu(l0 + adst));
    float w1 = __expf(lrelu(l1 + adst));
    float w2 = __expf(lrelu(l2 + adst));
    float w3 = __expf(lrelu(l3 + adst));
    acc2 += w0 * unp2(v0); acc2 += w1 * unp2(v1);
    acc2 += w2 * unp2(v2); acc2 += w3 * unp2(v3);
    dsum += w0 + w1 + w2 + w3;
  }
  for (; e < end; e += 2) {
    int s = csr_src[e];
    float w = __expf(lrelu(as2[s] + adst));
    uint v = *reinterpret_cast<const uint*>(&h2b[(size_t)s * OUT_C + sl * 2]);
    acc2 += w * unp2(v);
    dsum += w;
  }
  acc2.x += __shfl_xor(acc2.x, 32);
  acc2.y += __shfl_xor(acc2.y, 32);
  dsum += __shfl_xor(dsum, 32);
  float inv = 1.f / (dsum + 1e-16f);
  if (half == 0) {
    float2 o = {acc2.x * inv + b2[sl * 2], acc2.y * inv + b2[sl * 2 + 1]};
    *reinterpret_cast<float2*>(&out[(size_t)node * OUT_C + sl * 2]) = o;
  }
}

extern "C" void kernel_launch(void* const* d_in, const int* in_sizes, int n_in,
                              void* d_out, int out_size, void* d_ws, size_t ws_size,
                              hipStream_t stream) {
  const float* x     = (const float*)d_in[0];
  const int*   ei    = (const int*)d_in[1];
  const float* W1    = (const float*)d_in[2];
  const float* asrc1 = (const float*)d_in[3];
  const float* adst1 = (const float*)d_in[4];
  const float* b1    = (const float*)d_in[5];
  const float* W2    = (const float*)d_in[6];
  const float* asrc2 = (const float*)d_in[7];
  const float* adst2 = (const float*)d_in[8];
  const float* b2    = (const float*)d_in[9];
  float* out = (float*)d_out;

  char* p = (char*)d_ws;
  size_t off = 0;
  auto take = [&](size_t bytes) -> void* {
    void* r = p + off;
    off += (bytes + 255) & ~(size_t)255;
    return r;
  };
  ushort_t* h1b  = (ushort_t*)take((size_t)N_NODES * HID * 2);
  ushort_t* hpb  = (ushort_t*)take((size_t)(M_PAD / 128) * 8 * 4096 * 2);
  ushort_t* h2b  = (ushort_t*)take((size_t)N_NODES * OUT_C * 2);
  float*    as1p = (float*)take((size_t)N_NODES * HEADS * 4);
  float*    ad1p = (float*)take((size_t)N_NODES * HEADS * 4);
  float*    as2  = (float*)take((size_t)N_NODES * 4);
  float*    ad2  = (float*)take((size_t)N_NODES * 4);
  int* counts = (int*)take((size_t)N_NODES * 4);
  int* indptr = (int*)take((size_t)(N_NODES + 1) * 4);
  int* wptr   = (int*)take((size_t)(N_NODES + 1) * 4);
  int* bsum   = (int*)take((size_t)NBLK * 4);
  int* boff   = (int*)take((size_t)NBLK * 4);
  int* csr    = (int*)take((size_t)E_TOT * 4);
  ushort_t* w1t = (ushort_t*)take((size_t)IN_C * HID * 2);
  ushort_t* w2t = (ushort_t*)take((size_t)HID * OUT_C * 2);

  // CSR build (parallel scan)
  hipMemsetAsync(counts, 0, (size_t)N_NODES * 4, stream);
  k_count<<<(E_TOT + 255) / 256, 256, 0, stream>>>(ei, counts);
  k_bsum<<<NBLK, 256, 0, stream>>>(counts, bsum);
  k_bscan<<<1, 256, 0, stream>>>(bsum, boff);
  k_local<<<NBLK, 256, 0, stream>>>(counts, boff, indptr, wptr);
  k_scatter<<<(E_TOT + 255) / 256, 256, 0, stream>>>(ei, wptr, csr);

  // weight transposes
  k_conv_w1<<<(HID * IN_C + 255) / 256, 256, 0, stream>>>(W1, w1t);
  k_conv_w2<<<(OUT_C * HID + 255) / 256, 256, 0, stream>>>(W2, w2t);

  // layer 1
  k_mm1<<<M_PAD / 128, 512, 0, stream>>>(x, w1t, h1b);
  k_alpha1<<<(N_NODES * HEADS + 255) / 256, 256, 0, stream>>>(h1b, asrc1, adst1, as1p, ad1p);
  k_agg1<<<(N_NODES / 4) * 8, 256, 0, stream>>>(h1b, indptr, csr, as1p, ad1p, b1, hpb);

  // layer 2
  k_mm2<<<M_PAD / 128, 256, 0, stream>>>(hpb, w2t, h2b);
  k_alpha2<<<(N_NODES + 3) / 4, 256, 0, stream>>>(h2b, asrc2, adst2, as2, ad2);
  k_agg2<<<(N_NODES + 3) / 4, 256, 0, stream>>>(h2b, indptr, csr, as2, ad2, b2, out);
}

// Round 12
// 279.530 us; speedup vs baseline: 1.7861x; 1.7861x over previous
//
#include <hip/hip_runtime.h>

#define N_NODES 50000
#define M_PAD   50048            // 391 * 128
#define NBLK    196              // ceil(N_NODES/256)
#define E_EDGES 800000
#define E_TOT   (E_EDGES + N_NODES)
#define IN_C 512
#define HID 256
#define HEADS 8
#define OUT_C 64

typedef unsigned int uint;
typedef unsigned short ushort_t;
typedef __bf16 bf16x8 __attribute__((ext_vector_type(8)));
typedef float f32x4 __attribute__((ext_vector_type(4)));
typedef float f32x2 __attribute__((ext_vector_type(2)));

__device__ __forceinline__ float lrelu(float x) { return x > 0.f ? x : 0.2f * x; }

__device__ __forceinline__ unsigned short f2bf(float f) {
  uint u = __float_as_uint(f);
  u += 0x7FFF + ((u >> 16) & 1);          // RNE
  return (unsigned short)(u >> 16);
}
__device__ __forceinline__ float bflo(uint u) { return __uint_as_float(u << 16); }
__device__ __forceinline__ float bfhi(uint u) { return __uint_as_float(u & 0xFFFF0000u); }
__device__ __forceinline__ float bf2f(ushort_t u) { return __uint_as_float(((uint)u) << 16); }
__device__ __forceinline__ f32x2 unp2(uint u) {
  f32x2 r; r.x = bflo(u); r.y = bfhi(u); return r;
}

// ---------------- CSR build ----------------
__global__ void k_count(const int* __restrict__ ei, int* __restrict__ counts) {
  int e = blockIdx.x * blockDim.x + threadIdx.x;
  if (e >= E_TOT) return;
  int d = (e < E_EDGES) ? ei[E_EDGES + e] : (e - E_EDGES);
  atomicAdd(&counts[d], 1);
}

__global__ void k_bsum(const int* __restrict__ counts, int* __restrict__ bsum) {
  int i = blockIdx.x * 256 + threadIdx.x;
  int v = (i < N_NODES) ? counts[i] : 0;
  __shared__ int ws[4];
  int lane = threadIdx.x & 63, wid = threadIdx.x >> 6;
  #pragma unroll
  for (int off = 32; off; off >>= 1) v += __shfl_xor(v, off);
  if (lane == 0) ws[wid] = v;
  __syncthreads();
  if (threadIdx.x == 0) bsum[blockIdx.x] = ws[0] + ws[1] + ws[2] + ws[3];
}

__global__ void k_bscan(const int* __restrict__ bsum, int* __restrict__ boff) {
  int tid = threadIdx.x;
  int v = (tid < NBLK) ? bsum[tid] : 0;
  int lane = tid & 63, wid = tid >> 6;
  int x = v;
  #pragma unroll
  for (int off = 1; off < 64; off <<= 1) {
    int t = __shfl_up(x, off);
    if (lane >= off) x += t;
  }
  __shared__ int ws[4];
  if (lane == 63) ws[wid] = x;
  __syncthreads();
  int woff = 0;
  for (int w = 0; w < wid; w++) woff += ws[w];
  if (tid < NBLK) boff[tid] = x + woff - v;   // exclusive
}

__global__ void k_local(const int* __restrict__ counts, const int* __restrict__ boff,
                        int* __restrict__ indptr, int* __restrict__ wptr) {
  int b = blockIdx.x;
  int i = b * 256 + threadIdx.x;
  int v = (i < N_NODES) ? counts[i] : 0;
  int lane = threadIdx.x & 63, wid = threadIdx.x >> 6;
  int x = v;
  #pragma unroll
  for (int off = 1; off < 64; off <<= 1) {
    int t = __shfl_up(x, off);
    if (lane >= off) x += t;
  }
  __shared__ int ws[4];
  if (lane == 63) ws[wid] = x;
  __syncthreads();
  int woff = boff[b];
  for (int w = 0; w < wid; w++) woff += ws[w];
  int excl = woff + x - v;
  if (i < N_NODES) { indptr[i] = excl; wptr[i] = excl; }
  if (b == 0 && threadIdx.x == 0) indptr[N_NODES] = E_TOT;
}

__global__ void k_scatter(const int* __restrict__ ei, int* __restrict__ wptr,
                          int* __restrict__ csr_src) {
  int e = blockIdx.x * blockDim.x + threadIdx.x;
  if (e >= E_TOT) return;
  int s, d;
  if (e < E_EDGES) { s = ei[e]; d = ei[E_EDGES + e]; }
  else { s = d = e - E_EDGES; }
  int pos = atomicAdd(&wptr[d], 1);
  csr_src[pos] = s;
}

// ---------------- weight transposes (tiny) ----------------
__global__ void k_conv_w1(const float* __restrict__ W1, ushort_t* __restrict__ w1t) {
  int t = blockIdx.x * blockDim.x + threadIdx.x;
  if (t >= HID * IN_C) return;
  int n = t >> 9, k = t & 511;
  w1t[t] = f2bf(W1[(size_t)k * HID + n]);
}
__global__ void k_conv_w2(const float* __restrict__ W2, ushort_t* __restrict__ w2t) {
  int t = blockIdx.x * blockDim.x + threadIdx.x;
  if (t >= OUT_C * HID) return;
  int n = t >> 8, k = t & 255;
  w2t[t] = f2bf(W2[(size_t)k * OUT_C + n]);
}

// ---------------- GEMM1: h1b = bf16(x @ W1) ----------------
__global__ __launch_bounds__(512) void k_mm1(const float* __restrict__ A,
                                             const ushort_t* __restrict__ Bt,
                                             ushort_t* __restrict__ Cb) {
  __shared__ ushort_t sA[128][40];
  __shared__ ushort_t sB[256][40];
  int tid = threadIdx.x;
  int wid = tid >> 6, lane = tid & 63;
  int wm = wid >> 2, wn = wid & 3;
  int lr = lane & 15, kg = lane >> 4;
  int row0 = blockIdx.x * 128;
  f32x4 acc[4][4] = {};

  for (int k0 = 0; k0 < IN_C; k0 += 32) {
    {
      int r = tid >> 2, cs = (tid & 3) * 8;
      int gr = row0 + r;
      unsigned short v[8];
      if (gr < N_NODES) {
        const float* src = A + (size_t)gr * IN_C + k0 + cs;
        float4 f0 = *reinterpret_cast<const float4*>(src);
        float4 f1 = *reinterpret_cast<const float4*>(src + 4);
        v[0] = f2bf(f0.x); v[1] = f2bf(f0.y); v[2] = f2bf(f0.z); v[3] = f2bf(f0.w);
        v[4] = f2bf(f1.x); v[5] = f2bf(f1.y); v[6] = f2bf(f1.z); v[7] = f2bf(f1.w);
      } else {
        #pragma unroll
        for (int i = 0; i < 8; i++) v[i] = 0;
      }
      uint4 pk;
      pk.x = v[0] | ((uint)v[1] << 16); pk.y = v[2] | ((uint)v[3] << 16);
      pk.z = v[4] | ((uint)v[5] << 16); pk.w = v[6] | ((uint)v[7] << 16);
      *reinterpret_cast<uint4*>(&sA[r][cs]) = pk;
    }
    {
      int n = tid >> 1, ks = (tid & 1) * 16;
      const ushort_t* src = Bt + (size_t)n * IN_C + k0 + ks;
      uint4 v0 = *reinterpret_cast<const uint4*>(src);
      uint4 v1 = *reinterpret_cast<const uint4*>(src + 8);
      *reinterpret_cast<uint4*>(&sB[n][ks]) = v0;
      *reinterpret_cast<uint4*>(&sB[n][ks + 8]) = v1;
    }
    __syncthreads();

    bf16x8 af[4], bfr[4];
    #pragma unroll
    for (int i = 0; i < 4; i++)
      af[i] = *reinterpret_cast<const bf16x8*>(&sA[wm * 64 + i * 16 + lr][kg * 8]);
    #pragma unroll
    for (int j = 0; j < 4; j++)
      bfr[j] = *reinterpret_cast<const bf16x8*>(&sB[wn * 64 + j * 16 + lr][kg * 8]);
    #pragma unroll
    for (int i = 0; i < 4; i++)
      #pragma unroll
      for (int j = 0; j < 4; j++)
        acc[i][j] = __builtin_amdgcn_mfma_f32_16x16x32_bf16(af[i], bfr[j], acc[i][j], 0, 0, 0);
    __syncthreads();
  }

  #pragma unroll
  for (int i = 0; i < 4; i++) {
    #pragma unroll
    for (int j = 0; j < 4; j++) {
      int gc = wn * 64 + j * 16 + lr;
      #pragma unroll
      for (int q = 0; q < 4; q++) {
        int gr = row0 + wm * 64 + i * 16 + kg * 4 + q;
        if (gr < N_NODES) Cb[(size_t)gr * HID + gc] = f2bf(acc[i][j][q]);
      }
    }
  }
}

// ---------------- GEMM2: h2b = bf16(hpb_tiled @ W2) ----------------
__global__ __launch_bounds__(256) void k_mm2(const ushort_t* __restrict__ At,
                                             const ushort_t* __restrict__ Bt,
                                             ushort_t* __restrict__ Cb) {
  __shared__ ushort_t sA[128][40];
  __shared__ ushort_t sB[64][40];
  int tid = threadIdx.x;
  int wid = tid >> 6, lane = tid & 63;
  int lr = lane & 15, kg = lane >> 4;
  int row0 = blockIdx.x * 128;
  f32x4 acc[2][4] = {};

  for (int kt = 0; kt < HID / 32; ++kt) {
    {
      const ushort_t* src = At + ((size_t)blockIdx.x * 8 + kt) * 4096 + tid * 16;
      uint4 v0 = *reinterpret_cast<const uint4*>(src);
      uint4 v1 = *reinterpret_cast<const uint4*>(src + 8);
      int r = tid >> 1, ks = (tid & 1) * 16;
      *reinterpret_cast<uint4*>(&sA[r][ks]) = v0;
      *reinterpret_cast<uint4*>(&sA[r][ks + 8]) = v1;
    }
    if (tid < 128) {
      int n = tid >> 1, ks = (tid & 1) * 16;
      const ushort_t* src = Bt + (size_t)n * HID + kt * 32 + ks;
      uint4 v0 = *reinterpret_cast<const uint4*>(src);
      uint4 v1 = *reinterpret_cast<const uint4*>(src + 8);
      *reinterpret_cast<uint4*>(&sB[n][ks]) = v0;
      *reinterpret_cast<uint4*>(&sB[n][ks + 8]) = v1;
    }
    __syncthreads();

    bf16x8 af[2], bfr[4];
    #pragma unroll
    for (int i = 0; i < 2; i++)
      af[i] = *reinterpret_cast<const bf16x8*>(&sA[wid * 32 + i * 16 + lr][kg * 8]);
    #pragma unroll
    for (int j = 0; j < 4; j++)
      bfr[j] = *reinterpret_cast<const bf16x8*>(&sB[j * 16 + lr][kg * 8]);
    #pragma unroll
    for (int i = 0; i < 2; i++)
      #pragma unroll
      for (int j = 0; j < 4; j++)
        acc[i][j] = __builtin_amdgcn_mfma_f32_16x16x32_bf16(af[i], bfr[j], acc[i][j], 0, 0, 0);
    __syncthreads();
  }

  #pragma unroll
  for (int i = 0; i < 2; i++) {
    #pragma unroll
    for (int j = 0; j < 4; j++) {
      int gc = j * 16 + lr;
      #pragma unroll
      for (int q = 0; q < 4; q++) {
        int gr = row0 + wid * 32 + i * 16 + kg * 4 + q;
        if (gr < N_NODES) Cb[(size_t)gr * OUT_C + gc] = f2bf(acc[i][j][q]);
      }
    }
  }
}

// ---------------- attention logits ----------------
__global__ void k_alpha1(const ushort_t* __restrict__ h1b, const float* __restrict__ a_src,
                         const float* __restrict__ a_dst, float* __restrict__ as1,
                         float* __restrict__ ad1) {
  int t = blockIdx.x * blockDim.x + threadIdx.x;
  if (t >= N_NODES * HEADS) return;
  int n = t >> 3, h = t & 7;
  const ushort_t* row = h1b + (size_t)n * HID + h * 32;
  const float* asr = a_src + h * 32;
  const float* adr = a_dst + h * 32;
  float ss = 0.f, sd = 0.f;
  #pragma unroll
  for (int c = 0; c < 32; c += 8) {
    uint4 rv = *reinterpret_cast<const uint4*>(row + c);
    uint uu[4] = {rv.x, rv.y, rv.z, rv.w};
    #pragma unroll
    for (int q = 0; q < 4; q++) {
      float f0 = bflo(uu[q]), f1 = bfhi(uu[q]);
      ss += f0 * asr[c + q * 2] + f1 * asr[c + q * 2 + 1];
      sd += f0 * adr[c + q * 2] + f1 * adr[c + q * 2 + 1];
    }
  }
  as1[t] = ss;
  ad1[t] = sd;
}

__global__ void k_alpha2(const ushort_t* __restrict__ h2b, const float* __restrict__ a_src,
                         const float* __restrict__ a_dst, float* __restrict__ as2,
                         float* __restrict__ ad2) {
  int wave = threadIdx.x >> 6, lane = threadIdx.x & 63;
  int n = blockIdx.x * 4 + wave;
  if (n >= N_NODES) return;
  float v = bf2f(h2b[(size_t)n * OUT_C + lane]);
  float ss = v * a_src[lane];
  float sd = v * a_dst[lane];
  #pragma unroll
  for (int off = 32; off; off >>= 1) {
    ss += __shfl_xor(ss, off);
    sd += __shfl_xor(sd, off);
  }
  if (lane == 0) { as2[n] = ss; ad2[n] = sd; }
}

// ---------------- layer-1 aggregation: unroll-4 per half (R8 structure, best measured) ----------------
__global__ __launch_bounds__(256) void k_agg1(const ushort_t* __restrict__ h1b,
                                              const int* __restrict__ indptr,
                                              const int* __restrict__ csr_src,
                                              const float* __restrict__ as1,
                                              const float* __restrict__ ad1,
                                              const float* __restrict__ b1,
                                              ushort_t* __restrict__ hpb) {
  int wave = threadIdx.x >> 6, lane = threadIdx.x & 63;
  int node = blockIdx.x * 4 + wave;
  if (node >= N_NODES) return;
  int beg = indptr[node], end = indptr[node + 1];
  int half = lane >> 5, sl = lane & 31, h = sl >> 2;   // lane sl covers cols sl*8..sl*8+7
  float adst = ad1[node * 8 + h];

  f32x2 a0 = {0.f, 0.f}, a1 = {0.f, 0.f}, a2 = {0.f, 0.f}, a3 = {0.f, 0.f};
  float dsum = 0.f;
  int e = beg + half;
  for (; e + 6 < end; e += 8) {        // 4 edges per iter in this half's stride
    int s0 = csr_src[e];
    int s1 = csr_src[e + 2];
    int s2 = csr_src[e + 4];
    int s3 = csr_src[e + 6];
    float l0 = as1[s0 * 8 + h];
    float l1 = as1[s1 * 8 + h];
    float l2 = as1[s2 * 8 + h];
    float l3 = as1[s3 * 8 + h];
    uint4 r0 = *reinterpret_cast<const uint4*>(&h1b[(size_t)s0 * HID + sl * 8]);
    uint4 r1 = *reinterpret_cast<const uint4*>(&h1b[(size_t)s1 * HID + sl * 8]);
    uint4 r2 = *reinterpret_cast<const uint4*>(&h1b[(size_t)s2 * HID + sl * 8]);
    uint4 r3 = *reinterpret_cast<const uint4*>(&h1b[(size_t)s3 * HID + sl * 8]);
    float w0 = __expf(lrelu(l0 + adst));
    float w1 = __expf(lrelu(l1 + adst));
    float w2 = __expf(lrelu(l2 + adst));
    float w3 = __expf(lrelu(l3 + adst));
    a0 += w0 * unp2(r0.x); a1 += w0 * unp2(r0.y); a2 += w0 * unp2(r0.z); a3 += w0 * unp2(r0.w);
    a0 += w1 * unp2(r1.x); a1 += w1 * unp2(r1.y); a2 += w1 * unp2(r1.z); a3 += w1 * unp2(r1.w);
    a0 += w2 * unp2(r2.x); a1 += w2 * unp2(r2.y); a2 += w2 * unp2(r2.z); a3 += w2 * unp2(r2.w);
    a0 += w3 * unp2(r3.x); a1 += w3 * unp2(r3.y); a2 += w3 * unp2(r3.z); a3 += w3 * unp2(r3.w);
    dsum += w0 + w1 + w2 + w3;
  }
  for (; e < end; e += 2) {
    int s = csr_src[e];
    float w = __expf(lrelu(as1[s * 8 + h] + adst));
    uint4 rv = *reinterpret_cast<const uint4*>(&h1b[(size_t)s * HID + sl * 8]);
    a0 += w * unp2(rv.x); a1 += w * unp2(rv.y); a2 += w * unp2(rv.z); a3 += w * unp2(rv.w);
    dsum += w;
  }
  float acc[8] = {a0.x, a0.y, a1.x, a1.y, a2.x, a2.y, a3.x, a3.y};
  #pragma unroll
  for (int j = 0; j < 8; j++) acc[j] += __shfl_xor(acc[j], 32);
  dsum += __shfl_xor(dsum, 32);
  float inv = 1.f / (dsum + 1e-16f);

  if (half == 0) {
    unsigned short ob[8];
    #pragma unroll
    for (int j = 0; j < 8; j++) {
      float o = acc[j] * inv + b1[sl * 8 + j];
      o = o > 0.f ? o : expm1f(o);
      ob[j] = f2bf(o);
    }
    uint4 pk;
    pk.x = ob[0] | ((uint)ob[1] << 16); pk.y = ob[2] | ((uint)ob[3] << 16);
    pk.z = ob[4] | ((uint)ob[5] << 16); pk.w = ob[6] | ((uint)ob[7] << 16);
    size_t addr = ((size_t)(node >> 7) * 8 + (sl >> 2)) * 4096 + (size_t)(node & 127) * 32 + (sl & 3) * 8;
    *reinterpret_cast<uint4*>(&hpb[addr]) = pk;
  }
}

// ---------------- layer-2 aggregation: bf16 gather, unroll-4 (validated in R11 run) ----------------
__global__ __launch_bounds__(256) void k_agg2(const ushort_t* __restrict__ h2b,
                                              const int* __restrict__ indptr,
                                              const int* __restrict__ csr_src,
                                              const float* __restrict__ as2,
                                              const float* __restrict__ ad2,
                                              const float* __restrict__ b2,
                                              float* __restrict__ out) {
  int wave = threadIdx.x >> 6, lane = threadIdx.x & 63;
  int node = blockIdx.x * 4 + wave;
  if (node >= N_NODES) return;
  int beg = indptr[node], end = indptr[node + 1];
  int half = lane >> 5, sl = lane & 31;   // lane sl covers ch 2sl, 2sl+1 (4B bf16x2)
  float adst = ad2[node];

  f32x2 acc2 = {0.f, 0.f};
  float dsum = 0.f;
  int e = beg + half;
  for (; e + 6 < end; e += 8) {
    int s0 = csr_src[e];
    int s1 = csr_src[e + 2];
    int s2 = csr_src[e + 4];
    int s3 = csr_src[e + 6];
    float l0 = as2[s0];
    float l1 = as2[s1];
    float l2 = as2[s2];
    float l3 = as2[s3];
    uint v0 = *reinterpret_cast<const uint*>(&h2b[(size_t)s0 * OUT_C + sl * 2]);
    uint v1 = *reinterpret_cast<const uint*>(&h2b[(size_t)s1 * OUT_C + sl * 2]);
    uint v2 = *reinterpret_cast<const uint*>(&h2b[(size_t)s2 * OUT_C + sl * 2]);
    uint v3 = *reinterpret_cast<const uint*>(&h2b[(size_t)s3 * OUT_C + sl * 2]);
    float w0 = __expf(lrelu(l0 + adst));
    float w1 = __expf(lrelu(l1 + adst));
    float w2 = __expf(lrelu(l2 + adst));
    float w3 = __expf(lrelu(l3 + adst));
    acc2 += w0 * unp2(v0); acc2 += w1 * unp2(v1);
    acc2 += w2 * unp2(v2); acc2 += w3 * unp2(v3);
    dsum += w0 + w1 + w2 + w3;
  }
  for (; e < end; e += 2) {
    int s = csr_src[e];
    float w = __expf(lrelu(as2[s] + adst));
    uint v = *reinterpret_cast<const uint*>(&h2b[(size_t)s * OUT_C + sl * 2]);
    acc2 += w * unp2(v);
    dsum += w;
  }
  acc2.x += __shfl_xor(acc2.x, 32);
  acc2.y += __shfl_xor(acc2.y, 32);
  dsum += __shfl_xor(dsum, 32);
  float inv = 1.f / (dsum + 1e-16f);
  if (half == 0) {
    float2 o = {acc2.x * inv + b2[sl * 2], acc2.y * inv + b2[sl * 2 + 1]};
    *reinterpret_cast<float2*>(&out[(size_t)node * OUT_C + sl * 2]) = o;
  }
}

extern "C" void kernel_launch(void* const* d_in, const int* in_sizes, int n_in,
                              void* d_out, int out_size, void* d_ws, size_t ws_size,
                              hipStream_t stream) {
  const float* x     = (const float*)d_in[0];
  const int*   ei    = (const int*)d_in[1];
  const float* W1    = (const float*)d_in[2];
  const float* asrc1 = (const float*)d_in[3];
  const float* adst1 = (const float*)d_in[4];
  const float* b1    = (const float*)d_in[5];
  const float* W2    = (const float*)d_in[6];
  const float* asrc2 = (const float*)d_in[7];
  const float* adst2 = (const float*)d_in[8];
  const float* b2    = (const float*)d_in[9];
  float* out = (float*)d_out;

  char* p = (char*)d_ws;
  size_t off = 0;
  auto take = [&](size_t bytes) -> void* {
    void* r = p + off;
    off += (bytes + 255) & ~(size_t)255;
    return r;
  };
  ushort_t* h1b  = (ushort_t*)take((size_t)N_NODES * HID * 2);
  ushort_t* hpb  = (ushort_t*)take((size_t)(M_PAD / 128) * 8 * 4096 * 2);
  ushort_t* h2b  = (ushort_t*)take((size_t)N_NODES * OUT_C * 2);
  float*    as1  = (float*)take((size_t)N_NODES * HEADS * 4);
  float*    ad1  = (float*)take((size_t)N_NODES * HEADS * 4);
  float*    as2  = (float*)take((size_t)N_NODES * 4);
  float*    ad2  = (float*)take((size_t)N_NODES * 4);
  int* counts = (int*)take((size_t)N_NODES * 4);
  int* indptr = (int*)take((size_t)(N_NODES + 1) * 4);
  int* wptr   = (int*)take((size_t)(N_NODES + 1) * 4);
  int* bsum   = (int*)take((size_t)NBLK * 4);
  int* boff   = (int*)take((size_t)NBLK * 4);
  int* csr    = (int*)take((size_t)E_TOT * 4);
  ushort_t* w1t = (ushort_t*)take((size_t)IN_C * HID * 2);
  ushort_t* w2t = (ushort_t*)take((size_t)HID * OUT_C * 2);

  // CSR build (parallel scan)
  hipMemsetAsync(counts, 0, (size_t)N_NODES * 4, stream);
  k_count<<<(E_TOT + 255) / 256, 256, 0, stream>>>(ei, counts);
  k_bsum<<<NBLK, 256, 0, stream>>>(counts, bsum);
  k_bscan<<<1, 256, 0, stream>>>(bsum, boff);
  k_local<<<NBLK, 256, 0, stream>>>(counts, boff, indptr, wptr);
  k_scatter<<<(E_TOT + 255) / 256, 256, 0, stream>>>(ei, wptr, csr);

  // weight transposes
  k_conv_w1<<<(HID * IN_C + 255) / 256, 256, 0, stream>>>(W1, w1t);
  k_conv_w2<<<(OUT_C * HID + 255) / 256, 256, 0, stream>>>(W2, w2t);

  // layer 1
  k_mm1<<<M_PAD / 128, 512, 0, stream>>>(x, w1t, h1b);
  k_alpha1<<<(N_NODES * HEADS + 255) / 256, 256, 0, stream>>>(h1b, asrc1, adst1, as1, ad1);
  k_agg1<<<(N_NODES + 3) / 4, 256, 0, stream>>>(h1b, indptr, csr, as1, ad1, b1, hpb);

  // layer 2
  k_mm2<<<M_PAD / 128, 256, 0, stream>>>(hpb, w2t, h2b);
  k_alpha2<<<(N_NODES + 3) / 4, 256, 0, stream>>>(h2b, asrc2, adst2, as2, ad2);
  k_agg2<<<(N_NODES + 3) / 4, 256, 0, stream>>>(h2b, indptr, csr, as2, ad2, b2, out);
}

// Round 13
// 265.544 us; speedup vs baseline: 1.8801x; 1.0527x over previous
//
#include <hip/hip_runtime.h>

#define N_NODES 50000
#define M_PAD   50048            // 391 * 128
#define NBLK    196              // ceil(N_NODES/256)
#define E_EDGES 800000
#define E_TOT   (E_EDGES + N_NODES)
#define IN_C 512
#define HID 256
#define HEADS 8
#define OUT_C 64

typedef unsigned int uint;
typedef unsigned short ushort_t;
typedef __bf16 bf16x8 __attribute__((ext_vector_type(8)));
typedef float f32x4 __attribute__((ext_vector_type(4)));
typedef float f32x2 __attribute__((ext_vector_type(2)));

__device__ __forceinline__ float lrelu(float x) { return x > 0.f ? x : 0.2f * x; }

__device__ __forceinline__ unsigned short f2bf(float f) {
  __bf16 b = (__bf16)f;                       // compiler RNE cvt (v_cvt_pk_bf16_f32)
  return __builtin_bit_cast(unsigned short, b);
}
__device__ __forceinline__ float bflo(uint u) { return __uint_as_float(u << 16); }
__device__ __forceinline__ float bfhi(uint u) { return __uint_as_float(u & 0xFFFF0000u); }
__device__ __forceinline__ f32x2 unp2(uint u) {
  f32x2 r; r.x = bflo(u); r.y = bfhi(u); return r;
}

// ---------------- CSR build ----------------
__global__ void k_count(const int* __restrict__ ei, int* __restrict__ counts) {
  int e = blockIdx.x * blockDim.x + threadIdx.x;
  if (e >= E_TOT) return;
  int d = (e < E_EDGES) ? ei[E_EDGES + e] : (e - E_EDGES);
  atomicAdd(&counts[d], 1);
}

__global__ void k_bsum(const int* __restrict__ counts, int* __restrict__ bsum) {
  int i = blockIdx.x * 256 + threadIdx.x;
  int v = (i < N_NODES) ? counts[i] : 0;
  __shared__ int ws[4];
  int lane = threadIdx.x & 63, wid = threadIdx.x >> 6;
  #pragma unroll
  for (int off = 32; off; off >>= 1) v += __shfl_xor(v, off);
  if (lane == 0) ws[wid] = v;
  __syncthreads();
  if (threadIdx.x == 0) bsum[blockIdx.x] = ws[0] + ws[1] + ws[2] + ws[3];
}

__global__ void k_bscan(const int* __restrict__ bsum, int* __restrict__ boff) {
  int tid = threadIdx.x;
  int v = (tid < NBLK) ? bsum[tid] : 0;
  int lane = tid & 63, wid = tid >> 6;
  int x = v;
  #pragma unroll
  for (int off = 1; off < 64; off <<= 1) {
    int t = __shfl_up(x, off);
    if (lane >= off) x += t;
  }
  __shared__ int ws[4];
  if (lane == 63) ws[wid] = x;
  __syncthreads();
  int woff = 0;
  for (int w = 0; w < wid; w++) woff += ws[w];
  if (tid < NBLK) boff[tid] = x + woff - v;   // exclusive
}

__global__ void k_local(const int* __restrict__ counts, const int* __restrict__ boff,
                        int* __restrict__ indptr, int* __restrict__ wptr) {
  int b = blockIdx.x;
  int i = b * 256 + threadIdx.x;
  int v = (i < N_NODES) ? counts[i] : 0;
  int lane = threadIdx.x & 63, wid = threadIdx.x >> 6;
  int x = v;
  #pragma unroll
  for (int off = 1; off < 64; off <<= 1) {
    int t = __shfl_up(x, off);
    if (lane >= off) x += t;
  }
  __shared__ int ws[4];
  if (lane == 63) ws[wid] = x;
  __syncthreads();
  int woff = boff[b];
  for (int w = 0; w < wid; w++) woff += ws[w];
  int excl = woff + x - v;
  if (i < N_NODES) { indptr[i] = excl; wptr[i] = excl; }
  if (b == 0 && threadIdx.x == 0) indptr[N_NODES] = E_TOT;
}

__global__ void k_scatter(const int* __restrict__ ei, int* __restrict__ wptr,
                          int* __restrict__ csr_src) {
  int e = blockIdx.x * blockDim.x + threadIdx.x;
  if (e >= E_TOT) return;
  int s, d;
  if (e < E_EDGES) { s = ei[e]; d = ei[E_EDGES + e]; }
  else { s = d = e - E_EDGES; }
  int pos = atomicAdd(&wptr[d], 1);
  csr_src[pos] = s;
}

// ---------------- weight transposes (merged, tiny) ----------------
__global__ void k_convw(const float* __restrict__ W1, const float* __restrict__ W2,
                        ushort_t* __restrict__ w1t, ushort_t* __restrict__ w2t) {
  int t = blockIdx.x * blockDim.x + threadIdx.x;
  if (t < HID * IN_C) {
    int n = t >> 9, k = t & 511;
    w1t[t] = f2bf(W1[(size_t)k * HID + n]);
  } else if (t < HID * IN_C + OUT_C * HID) {
    int u = t - HID * IN_C;
    int n = u >> 8, k = u & 255;
    w2t[u] = f2bf(W2[(size_t)k * OUT_C + n]);
  }
}

// ---------------- GEMM1 + fused alpha1: h1b = bf16(x@W1); as1/ad1 from fp32 acc ----------------
__global__ __launch_bounds__(512) void k_mm1(const float* __restrict__ A,
                                             const ushort_t* __restrict__ Bt,
                                             const float* __restrict__ asrc1,
                                             const float* __restrict__ adst1,
                                             ushort_t* __restrict__ Cb,
                                             float* __restrict__ as1,
                                             float* __restrict__ ad1) {
  __shared__ ushort_t sA[128][40];
  __shared__ ushort_t sB[256][40];
  int tid = threadIdx.x;
  int wid = tid >> 6, lane = tid & 63;
  int wm = wid >> 2, wn = wid & 3;
  int lr = lane & 15, kg = lane >> 4;
  int row0 = blockIdx.x * 128;
  f32x4 acc[4][4] = {};

  for (int k0 = 0; k0 < IN_C; k0 += 32) {
    {
      int r = tid >> 2, cs = (tid & 3) * 8;
      int gr = row0 + r;
      unsigned short v[8];
      if (gr < N_NODES) {
        const float* src = A + (size_t)gr * IN_C + k0 + cs;
        float4 f0 = *reinterpret_cast<const float4*>(src);
        float4 f1 = *reinterpret_cast<const float4*>(src + 4);
        v[0] = f2bf(f0.x); v[1] = f2bf(f0.y); v[2] = f2bf(f0.z); v[3] = f2bf(f0.w);
        v[4] = f2bf(f1.x); v[5] = f2bf(f1.y); v[6] = f2bf(f1.z); v[7] = f2bf(f1.w);
      } else {
        #pragma unroll
        for (int i = 0; i < 8; i++) v[i] = 0;
      }
      uint4 pk;
      pk.x = v[0] | ((uint)v[1] << 16); pk.y = v[2] | ((uint)v[3] << 16);
      pk.z = v[4] | ((uint)v[5] << 16); pk.w = v[6] | ((uint)v[7] << 16);
      *reinterpret_cast<uint4*>(&sA[r][cs]) = pk;
    }
    {
      int n = tid >> 1, ks = (tid & 1) * 16;
      const ushort_t* src = Bt + (size_t)n * IN_C + k0 + ks;
      uint4 v0 = *reinterpret_cast<const uint4*>(src);
      uint4 v1 = *reinterpret_cast<const uint4*>(src + 8);
      *reinterpret_cast<uint4*>(&sB[n][ks]) = v0;
      *reinterpret_cast<uint4*>(&sB[n][ks + 8]) = v1;
    }
    __syncthreads();

    bf16x8 af[4], bfr[4];
    #pragma unroll
    for (int i = 0; i < 4; i++)
      af[i] = *reinterpret_cast<const bf16x8*>(&sA[wm * 64 + i * 16 + lr][kg * 8]);
    #pragma unroll
    for (int j = 0; j < 4; j++)
      bfr[j] = *reinterpret_cast<const bf16x8*>(&sB[wn * 64 + j * 16 + lr][kg * 8]);
    #pragma unroll
    for (int i = 0; i < 4; i++)
      #pragma unroll
      for (int j = 0; j < 4; j++)
        acc[i][j] = __builtin_amdgcn_mfma_f32_16x16x32_bf16(af[i], bfr[j], acc[i][j], 0, 0, 0);
    __syncthreads();
  }

  // fused alpha1: heads 2wn, 2wn+1 from fp32 acc; reduce across lr lanes
  {
    int h0 = wn * 2, h1 = wn * 2 + 1;
    float a0s = asrc1[h0 * 32 + lr], a1s = asrc1[h0 * 32 + 16 + lr];
    float a2s = asrc1[h1 * 32 + lr], a3s = asrc1[h1 * 32 + 16 + lr];
    float a0d = adst1[h0 * 32 + lr], a1d = adst1[h0 * 32 + 16 + lr];
    float a2d = adst1[h1 * 32 + lr], a3d = adst1[h1 * 32 + 16 + lr];
    #pragma unroll
    for (int i = 0; i < 4; i++) {
      #pragma unroll
      for (int q = 0; q < 4; q++) {
        float s0 = acc[i][0][q] * a0s + acc[i][1][q] * a1s;
        float s1 = acc[i][2][q] * a2s + acc[i][3][q] * a3s;
        float d0 = acc[i][0][q] * a0d + acc[i][1][q] * a1d;
        float d1 = acc[i][2][q] * a2d + acc[i][3][q] * a3d;
        #pragma unroll
        for (int off = 1; off < 16; off <<= 1) {
          s0 += __shfl_xor(s0, off);
          s1 += __shfl_xor(s1, off);
          d0 += __shfl_xor(d0, off);
          d1 += __shfl_xor(d1, off);
        }
        int gr = row0 + wm * 64 + i * 16 + kg * 4 + q;
        if (lr == 0 && gr < N_NODES) {
          as1[gr * 8 + h0] = s0;
          as1[gr * 8 + h1] = s1;
          ad1[gr * 8 + h0] = d0;
          ad1[gr * 8 + h1] = d1;
        }
      }
    }
  }

  #pragma unroll
  for (int i = 0; i < 4; i++) {
    #pragma unroll
    for (int j = 0; j < 4; j++) {
      int gc = wn * 64 + j * 16 + lr;
      #pragma unroll
      for (int q = 0; q < 4; q++) {
        int gr = row0 + wm * 64 + i * 16 + kg * 4 + q;
        if (gr < N_NODES) Cb[(size_t)gr * HID + gc] = f2bf(acc[i][j][q]);
      }
    }
  }
}

// ---------------- GEMM2 + fused alpha2: h2b = bf16(hpb@W2); as2/ad2 from fp32 acc ----------------
__global__ __launch_bounds__(256) void k_mm2(const ushort_t* __restrict__ At,
                                             const ushort_t* __restrict__ Bt,
                                             const float* __restrict__ asrc2,
                                             const float* __restrict__ adst2,
                                             ushort_t* __restrict__ Cb,
                                             float* __restrict__ as2,
                                             float* __restrict__ ad2) {
  __shared__ ushort_t sA[128][40];
  __shared__ ushort_t sB[64][40];
  int tid = threadIdx.x;
  int wid = tid >> 6, lane = tid & 63;
  int lr = lane & 15, kg = lane >> 4;
  int row0 = blockIdx.x * 128;
  f32x4 acc[2][4] = {};

  for (int kt = 0; kt < HID / 32; ++kt) {
    {
      const ushort_t* src = At + ((size_t)blockIdx.x * 8 + kt) * 4096 + tid * 16;
      uint4 v0 = *reinterpret_cast<const uint4*>(src);
      uint4 v1 = *reinterpret_cast<const uint4*>(src + 8);
      int r = tid >> 1, ks = (tid & 1) * 16;
      *reinterpret_cast<uint4*>(&sA[r][ks]) = v0;
      *reinterpret_cast<uint4*>(&sA[r][ks + 8]) = v1;
    }
    if (tid < 128) {
      int n = tid >> 1, ks = (tid & 1) * 16;
      const ushort_t* src = Bt + (size_t)n * HID + kt * 32 + ks;
      uint4 v0 = *reinterpret_cast<const uint4*>(src);
      uint4 v1 = *reinterpret_cast<const uint4*>(src + 8);
      *reinterpret_cast<uint4*>(&sB[n][ks]) = v0;
      *reinterpret_cast<uint4*>(&sB[n][ks + 8]) = v1;
    }
    __syncthreads();

    bf16x8 af[2], bfr[4];
    #pragma unroll
    for (int i = 0; i < 2; i++)
      af[i] = *reinterpret_cast<const bf16x8*>(&sA[wid * 32 + i * 16 + lr][kg * 8]);
    #pragma unroll
    for (int j = 0; j < 4; j++)
      bfr[j] = *reinterpret_cast<const bf16x8*>(&sB[j * 16 + lr][kg * 8]);
    #pragma unroll
    for (int i = 0; i < 2; i++)
      #pragma unroll
      for (int j = 0; j < 4; j++)
        acc[i][j] = __builtin_amdgcn_mfma_f32_16x16x32_bf16(af[i], bfr[j], acc[i][j], 0, 0, 0);
    __syncthreads();
  }

  // fused alpha2 from fp32 acc
  {
    float avs[4], avd[4];
    #pragma unroll
    for (int j = 0; j < 4; j++) {
      avs[j] = asrc2[j * 16 + lr];
      avd[j] = adst2[j * 16 + lr];
    }
    #pragma unroll
    for (int i = 0; i < 2; i++) {
      #pragma unroll
      for (int q = 0; q < 4; q++) {
        float s = acc[i][0][q] * avs[0] + acc[i][1][q] * avs[1]
                + acc[i][2][q] * avs[2] + acc[i][3][q] * avs[3];
        float d = acc[i][0][q] * avd[0] + acc[i][1][q] * avd[1]
                + acc[i][2][q] * avd[2] + acc[i][3][q] * avd[3];
        #pragma unroll
        for (int off = 1; off < 16; off <<= 1) {
          s += __shfl_xor(s, off);
          d += __shfl_xor(d, off);
        }
        int gr = row0 + wid * 32 + i * 16 + kg * 4 + q;
        if (lr == 0 && gr < N_NODES) { as2[gr] = s; ad2[gr] = d; }
      }
    }
  }

  #pragma unroll
  for (int i = 0; i < 2; i++) {
    #pragma unroll
    for (int j = 0; j < 4; j++) {
      int gc = j * 16 + lr;
      #pragma unroll
      for (int q = 0; q < 4; q++) {
        int gr = row0 + wid * 32 + i * 16 + kg * 4 + q;
        if (gr < N_NODES) Cb[(size_t)gr * OUT_C + gc] = f2bf(acc[i][j][q]);
      }
    }
  }
}

// ---------------- layer-1 aggregation: unroll-4 per half (R8 structure, measured floor) ----------------
__global__ __launch_bounds__(256) void k_agg1(const ushort_t* __restrict__ h1b,
                                              const int* __restrict__ indptr,
                                              const int* __restrict__ csr_src,
                                              const float* __restrict__ as1,
                                              const float* __restrict__ ad1,
                                              const float* __restrict__ b1,
                                              ushort_t* __restrict__ hpb) {
  int wave = threadIdx.x >> 6, lane = threadIdx.x & 63;
  int node = blockIdx.x * 4 + wave;
  if (node >= N_NODES) return;
  int beg = indptr[node], end = indptr[node + 1];
  int half = lane >> 5, sl = lane & 31, h = sl >> 2;   // lane sl covers cols sl*8..sl*8+7
  float adst = ad1[node * 8 + h];

  f32x2 a0 = {0.f, 0.f}, a1 = {0.f, 0.f}, a2 = {0.f, 0.f}, a3 = {0.f, 0.f};
  float dsum = 0.f;
  int e = beg + half;
  for (; e + 6 < end; e += 8) {        // 4 edges per iter in this half's stride
    int s0 = csr_src[e];
    int s1 = csr_src[e + 2];
    int s2 = csr_src[e + 4];
    int s3 = csr_src[e + 6];
    float l0 = as1[s0 * 8 + h];
    float l1 = as1[s1 * 8 + h];
    float l2 = as1[s2 * 8 + h];
    float l3 = as1[s3 * 8 + h];
    uint4 r0 = *reinterpret_cast<const uint4*>(&h1b[(size_t)s0 * HID + sl * 8]);
    uint4 r1 = *reinterpret_cast<const uint4*>(&h1b[(size_t)s1 * HID + sl * 8]);
    uint4 r2 = *reinterpret_cast<const uint4*>(&h1b[(size_t)s2 * HID + sl * 8]);
    uint4 r3 = *reinterpret_cast<const uint4*>(&h1b[(size_t)s3 * HID + sl * 8]);
    float w0 = __expf(lrelu(l0 + adst));
    float w1 = __expf(lrelu(l1 + adst));
    float w2 = __expf(lrelu(l2 + adst));
    float w3 = __expf(lrelu(l3 + adst));
    a0 += w0 * unp2(r0.x); a1 += w0 * unp2(r0.y); a2 += w0 * unp2(r0.z); a3 += w0 * unp2(r0.w);
    a0 += w1 * unp2(r1.x); a1 += w1 * unp2(r1.y); a2 += w1 * unp2(r1.z); a3 += w1 * unp2(r1.w);
    a0 += w2 * unp2(r2.x); a1 += w2 * unp2(r2.y); a2 += w2 * unp2(r2.z); a3 += w2 * unp2(r2.w);
    a0 += w3 * unp2(r3.x); a1 += w3 * unp2(r3.y); a2 += w3 * unp2(r3.z); a3 += w3 * unp2(r3.w);
    dsum += w0 + w1 + w2 + w3;
  }
  for (; e < end; e += 2) {
    int s = csr_src[e];
    float w = __expf(lrelu(as1[s * 8 + h] + adst));
    uint4 rv = *reinterpret_cast<const uint4*>(&h1b[(size_t)s * HID + sl * 8]);
    a0 += w * unp2(rv.x); a1 += w * unp2(rv.y); a2 += w * unp2(rv.z); a3 += w * unp2(rv.w);
    dsum += w;
  }
  float acc[8] = {a0.x, a0.y, a1.x, a1.y, a2.x, a2.y, a3.x, a3.y};
  #pragma unroll
  for (int j = 0; j < 8; j++) acc[j] += __shfl_xor(acc[j], 32);
  dsum += __shfl_xor(dsum, 32);
  float inv = 1.f / (dsum + 1e-16f);

  if (half == 0) {
    unsigned short ob[8];
    #pragma unroll
    for (int j = 0; j < 8; j++) {
      float o = acc[j] * inv + b1[sl * 8 + j];
      o = o > 0.f ? o : expm1f(o);
      ob[j] = f2bf(o);
    }
    uint4 pk;
    pk.x = ob[0] | ((uint)ob[1] << 16); pk.y = ob[2] | ((uint)ob[3] << 16);
    pk.z = ob[4] | ((uint)ob[5] << 16); pk.w = ob[6] | ((uint)ob[7] << 16);
    size_t addr = ((size_t)(node >> 7) * 8 + (sl >> 2)) * 4096 + (size_t)(node & 127) * 32 + (sl & 3) * 8;
    *reinterpret_cast<uint4*>(&hpb[addr]) = pk;
  }
}

// ---------------- layer-2 aggregation: bf16 gather, unroll-4 ----------------
__global__ __launch_bounds__(256) void k_agg2(const ushort_t* __restrict__ h2b,
                                              const int* __restrict__ indptr,
                                              const int* __restrict__ csr_src,
                                              const float* __restrict__ as2,
                                              const float* __restrict__ ad2,
                                              const float* __restrict__ b2,
                                              float* __restrict__ out) {
  int wave = threadIdx.x >> 6, lane = threadIdx.x & 63;
  int node = blockIdx.x * 4 + wave;
  if (node >= N_NODES) return;
  int beg = indptr[node], end = indptr[node + 1];
  int half = lane >> 5, sl = lane & 31;   // lane sl covers ch 2sl, 2sl+1 (4B bf16x2)
  float adst = ad2[node];

  f32x2 acc2 = {0.f, 0.f};
  float dsum = 0.f;
  int e = beg + half;
  for (; e + 6 < end; e += 8) {
    int s0 = csr_src[e];
    int s1 = csr_src[e + 2];
    int s2 = csr_src[e + 4];
    int s3 = csr_src[e + 6];
    float l0 = as2[s0];
    float l1 = as2[s1];
    float l2 = as2[s2];
    float l3 = as2[s3];
    uint v0 = *reinterpret_cast<const uint*>(&h2b[(size_t)s0 * OUT_C + sl * 2]);
    uint v1 = *reinterpret_cast<const uint*>(&h2b[(size_t)s1 * OUT_C + sl * 2]);
    uint v2 = *reinterpret_cast<const uint*>(&h2b[(size_t)s2 * OUT_C + sl * 2]);
    uint v3 = *reinterpret_cast<const uint*>(&h2b[(size_t)s3 * OUT_C + sl * 2]);
    float w0 = __expf(lrelu(l0 + adst));
    float w1 = __expf(lrelu(l1 + adst));
    float w2 = __expf(lrelu(l2 + adst));
    float w3 = __expf(lrelu(l3 + adst));
    acc2 += w0 * unp2(v0); acc2 += w1 * unp2(v1);
    acc2 += w2 * unp2(v2); acc2 += w3 * unp2(v3);
    dsum += w0 + w1 + w2 + w3;
  }
  for (; e < end; e += 2) {
    int s = csr_src[e];
    float w = __expf(lrelu(as2[s] + adst));
    uint v = *reinterpret_cast<const uint*>(&h2b[(size_t)s * OUT_C + sl * 2]);
    acc2 += w * unp2(v);
    dsum += w;
  }
  acc2.x += __shfl_xor(acc2.x, 32);
  acc2.y += __shfl_xor(acc2.y, 32);
  dsum += __shfl_xor(dsum, 32);
  float inv = 1.f / (dsum + 1e-16f);
  if (half == 0) {
    float2 o = {acc2.x * inv + b2[sl * 2], acc2.y * inv + b2[sl * 2 + 1]};
    *reinterpret_cast<float2*>(&out[(size_t)node * OUT_C + sl * 2]) = o;
  }
}

extern "C" void kernel_launch(void* const* d_in, const int* in_sizes, int n_in,
                              void* d_out, int out_size, void* d_ws, size_t ws_size,
                              hipStream_t stream) {
  const float* x     = (const float*)d_in[0];
  const int*   ei    = (const int*)d_in[1];
  const float* W1    = (const float*)d_in[2];
  const float* asrc1 = (const float*)d_in[3];
  const float* adst1 = (const float*)d_in[4];
  const float* b1    = (const float*)d_in[5];
  const float* W2    = (const float*)d_in[6];
  const float* asrc2 = (const float*)d_in[7];
  const float* adst2 = (const float*)d_in[8];
  const float* b2    = (const float*)d_in[9];
  float* out = (float*)d_out;

  char* p = (char*)d_ws;
  size_t off = 0;
  auto take = [&](size_t bytes) -> void* {
    void* r = p + off;
    off += (bytes + 255) & ~(size_t)255;
    return r;
  };
  ushort_t* h1b  = (ushort_t*)take((size_t)N_NODES * HID * 2);
  ushort_t* hpb  = (ushort_t*)take((size_t)(M_PAD / 128) * 8 * 4096 * 2);
  ushort_t* h2b  = (ushort_t*)take((size_t)N_NODES * OUT_C * 2);
  float*    as1  = (float*)take((size_t)N_NODES * HEADS * 4);
  float*    ad1  = (float*)take((size_t)N_NODES * HEADS * 4);
  float*    as2  = (float*)take((size_t)N_NODES * 4);
  float*    ad2  = (float*)take((size_t)N_NODES * 4);
  int* counts = (int*)take((size_t)N_NODES * 4);
  int* indptr = (int*)take((size_t)(N_NODES + 1) * 4);
  int* wptr   = (int*)take((size_t)(N_NODES + 1) * 4);
  int* bsum   = (int*)take((size_t)NBLK * 4);
  int* boff   = (int*)take((size_t)NBLK * 4);
  int* csr    = (int*)take((size_t)E_TOT * 4);
  ushort_t* w1t = (ushort_t*)take((size_t)IN_C * HID * 2);
  ushort_t* w2t = (ushort_t*)take((size_t)HID * OUT_C * 2);

  // CSR build (parallel scan)
  hipMemsetAsync(counts, 0, (size_t)N_NODES * 4, stream);
  k_count<<<(E_TOT + 255) / 256, 256, 0, stream>>>(ei, counts);
  k_bsum<<<NBLK, 256, 0, stream>>>(counts, bsum);
  k_bscan<<<1, 256, 0, stream>>>(bsum, boff);
  k_local<<<NBLK, 256, 0, stream>>>(counts, boff, indptr, wptr);
  k_scatter<<<(E_TOT + 255) / 256, 256, 0, stream>>>(ei, wptr, csr);

  // weight transposes (merged)
  k_convw<<<(HID * IN_C + OUT_C * HID + 255) / 256, 256, 0, stream>>>(W1, W2, w1t, w2t);

  // layer 1 (alpha fused into mm1)
  k_mm1<<<M_PAD / 128, 512, 0, stream>>>(x, w1t, asrc1, adst1, h1b, as1, ad1);
  k_agg1<<<(N_NODES + 3) / 4, 256, 0, stream>>>(h1b, indptr, csr, as1, ad1, b1, hpb);

  // layer 2 (alpha fused into mm2)
  k_mm2<<<M_PAD / 128, 256, 0, stream>>>(hpb, w2t, asrc2, adst2, h2b, as2, ad2);
  k_agg2<<<(N_NODES + 3) / 4, 256, 0, stream>>>(h2b, indptr, csr, as2, ad2, b2, out);
}

// Round 15
// 240.805 us; speedup vs baseline: 2.0733x; 1.1027x over previous
//
#include <hip/hip_runtime.h>

#define N_NODES 50000
#define M_PAD   50048            // 391 * 128
#define NBLK    196              // ceil(N_NODES/256)
#define E_EDGES 800000
#define E_TOT   (E_EDGES + N_NODES)
#define IN_C 512
#define HID 256
#define HEADS 8
#define OUT_C 64

#define MM1_BLOCKS (M_PAD / 128)                 // 391
#define SCAT_BLOCKS ((E_TOT + 511) / 512)        // 1661
#define CNT_BLOCKS  ((E_TOT + 511) / 512)        // 1661
#define CONVW_ELEMS (HID * IN_C + OUT_C * HID)   // 147456
#define CONVW_BLOCKS ((CONVW_ELEMS + 511) / 512) // 288

typedef unsigned int uint;
typedef unsigned short ushort_t;
typedef __bf16 bf16x8 __attribute__((ext_vector_type(8)));
typedef float f32x4 __attribute__((ext_vector_type(4)));
typedef float f32x2 __attribute__((ext_vector_type(2)));

__device__ __forceinline__ float lrelu(float x) { return x > 0.f ? x : 0.2f * x; }

__device__ __forceinline__ unsigned short f2bf(float f) {
  __bf16 b = (__bf16)f;                       // compiler RNE cvt
  return __builtin_bit_cast(unsigned short, b);
}
__device__ __forceinline__ float bflo(uint u) { return __uint_as_float(u << 16); }
__device__ __forceinline__ float bfhi(uint u) { return __uint_as_float(u & 0xFFFF0000u); }
__device__ __forceinline__ f32x2 unp2(uint u) {
  f32x2 r; r.x = bflo(u); r.y = bfhi(u); return r;
}

// ---------------- fatA: edge-count || weight transpose ----------------
__global__ __launch_bounds__(512) void k_fatA(const int* __restrict__ ei,
                                              int* __restrict__ counts,
                                              const float* __restrict__ W1,
                                              const float* __restrict__ W2,
                                              ushort_t* __restrict__ w1t,
                                              ushort_t* __restrict__ w2t) {
  int bid = blockIdx.x;
  if (bid < CNT_BLOCKS) {
    int e = bid * 512 + threadIdx.x;
    if (e >= E_TOT) return;
    int d = (e < E_EDGES) ? ei[E_EDGES + e] : (e - E_EDGES);
    atomicAdd(&counts[d], 1);
  } else {
    int t = (bid - CNT_BLOCKS) * 512 + threadIdx.x;
    if (t < HID * IN_C) {
      int n = t >> 9, k = t & 511;
      w1t[t] = f2bf(W1[(size_t)k * HID + n]);
    } else if (t < CONVW_ELEMS) {
      int u = t - HID * IN_C;
      int n = u >> 8, k = u & 255;
      w2t[u] = f2bf(W2[(size_t)k * OUT_C + n]);
    }
  }
}

// ---------------- scan kernels ----------------
__global__ void k_bsum(const int* __restrict__ counts, int* __restrict__ bsum) {
  int i = blockIdx.x * 256 + threadIdx.x;
  int v = (i < N_NODES) ? counts[i] : 0;
  __shared__ int ws[4];
  int lane = threadIdx.x & 63, wid = threadIdx.x >> 6;
  #pragma unroll
  for (int off = 32; off; off >>= 1) v += __shfl_xor(v, off);
  if (lane == 0) ws[wid] = v;
  __syncthreads();
  if (threadIdx.x == 0) bsum[blockIdx.x] = ws[0] + ws[1] + ws[2] + ws[3];
}

__global__ void k_bscan(const int* __restrict__ bsum, int* __restrict__ boff) {
  int tid = threadIdx.x;
  int v = (tid < NBLK) ? bsum[tid] : 0;
  int lane = tid & 63, wid = tid >> 6;
  int x = v;
  #pragma unroll
  for (int off = 1; off < 64; off <<= 1) {
    int t = __shfl_up(x, off);
    if (lane >= off) x += t;
  }
  __shared__ int ws[4];
  if (lane == 63) ws[wid] = x;
  __syncthreads();
  int woff = 0;
  for (int w = 0; w < wid; w++) woff += ws[w];
  if (tid < NBLK) boff[tid] = x + woff - v;   // exclusive
}

__global__ void k_local(const int* __restrict__ counts, const int* __restrict__ boff,
                        int* __restrict__ indptr, int* __restrict__ wptr) {
  int b = blockIdx.x;
  int i = b * 256 + threadIdx.x;
  int v = (i < N_NODES) ? counts[i] : 0;
  int lane = threadIdx.x & 63, wid = threadIdx.x >> 6;
  int x = v;
  #pragma unroll
  for (int off = 1; off < 64; off <<= 1) {
    int t = __shfl_up(x, off);
    if (lane >= off) x += t;
  }
  __shared__ int ws[4];
  if (lane == 63) ws[wid] = x;
  __syncthreads();
  int woff = boff[b];
  for (int w = 0; w < wid; w++) woff += ws[w];
  int excl = woff + x - v;
  if (i < N_NODES) { indptr[i] = excl; wptr[i] = excl; }
  if (b == 0 && threadIdx.x == 0) indptr[N_NODES] = E_TOT;
}

// ---------------- fatB: GEMM1+alpha1 (blocks 0..390) || scatter (rest) ----------------
__global__ __launch_bounds__(512) void k_fatB(const float* __restrict__ A,
                                              const ushort_t* __restrict__ Bt,
                                              const float* __restrict__ asrc1,
                                              const float* __restrict__ adst1,
                                              ushort_t* __restrict__ Cb,
                                              float* __restrict__ as1,
                                              float* __restrict__ ad1,
                                              const int* __restrict__ ei,
                                              int* __restrict__ wptr,
                                              int* __restrict__ csr_src) {
  if (blockIdx.x >= MM1_BLOCKS) {
    // ---- scatter part ----
    int e = (blockIdx.x - MM1_BLOCKS) * 512 + threadIdx.x;
    if (e >= E_TOT) return;
    int s, d;
    if (e < E_EDGES) { s = ei[e]; d = ei[E_EDGES + e]; }
    else { s = d = e - E_EDGES; }
    int pos = atomicAdd(&wptr[d], 1);
    csr_src[pos] = s;
    return;
  }
  // ---- mm1 part (identical to R13 k_mm1) ----
  __shared__ ushort_t sA[128][40];
  __shared__ ushort_t sB[256][40];
  int tid = threadIdx.x;
  int wid = tid >> 6, lane = tid & 63;
  int wm = wid >> 2, wn = wid & 3;
  int lr = lane & 15, kg = lane >> 4;
  int row0 = blockIdx.x * 128;
  f32x4 acc[4][4] = {};

  for (int k0 = 0; k0 < IN_C; k0 += 32) {
    {
      int r = tid >> 2, cs = (tid & 3) * 8;
      int gr = row0 + r;
      unsigned short v[8];
      if (gr < N_NODES) {
        const float* src = A + (size_t)gr * IN_C + k0 + cs;
        float4 f0 = *reinterpret_cast<const float4*>(src);
        float4 f1 = *reinterpret_cast<const float4*>(src + 4);
        v[0] = f2bf(f0.x); v[1] = f2bf(f0.y); v[2] = f2bf(f0.z); v[3] = f2bf(f0.w);
        v[4] = f2bf(f1.x); v[5] = f2bf(f1.y); v[6] = f2bf(f1.z); v[7] = f2bf(f1.w);
      } else {
        #pragma unroll
        for (int i = 0; i < 8; i++) v[i] = 0;
      }
      uint4 pk;
      pk.x = v[0] | ((uint)v[1] << 16); pk.y = v[2] | ((uint)v[3] << 16);
      pk.z = v[4] | ((uint)v[5] << 16); pk.w = v[6] | ((uint)v[7] << 16);
      *reinterpret_cast<uint4*>(&sA[r][cs]) = pk;
    }
    {
      int n = tid >> 1, ks = (tid & 1) * 16;
      const ushort_t* src = Bt + (size_t)n * IN_C + k0 + ks;
      uint4 v0 = *reinterpret_cast<const uint4*>(src);
      uint4 v1 = *reinterpret_cast<const uint4*>(src + 8);
      *reinterpret_cast<uint4*>(&sB[n][ks]) = v0;
      *reinterpret_cast<uint4*>(&sB[n][ks + 8]) = v1;
    }
    __syncthreads();

    bf16x8 af[4], bfr[4];
    #pragma unroll
    for (int i = 0; i < 4; i++)
      af[i] = *reinterpret_cast<const bf16x8*>(&sA[wm * 64 + i * 16 + lr][kg * 8]);
    #pragma unroll
    for (int j = 0; j < 4; j++)
      bfr[j] = *reinterpret_cast<const bf16x8*>(&sB[wn * 64 + j * 16 + lr][kg * 8]);
    #pragma unroll
    for (int i = 0; i < 4; i++)
      #pragma unroll
      for (int j = 0; j < 4; j++)
        acc[i][j] = __builtin_amdgcn_mfma_f32_16x16x32_bf16(af[i], bfr[j], acc[i][j], 0, 0, 0);
    __syncthreads();
  }

  // fused alpha1: heads 2wn, 2wn+1 from fp32 acc; reduce across lr lanes
  {
    int h0 = wn * 2, h1 = wn * 2 + 1;
    float a0s = asrc1[h0 * 32 + lr], a1s = asrc1[h0 * 32 + 16 + lr];
    float a2s = asrc1[h1 * 32 + lr], a3s = asrc1[h1 * 32 + 16 + lr];
    float a0d = adst1[h0 * 32 + lr], a1d = adst1[h0 * 32 + 16 + lr];
    float a2d = adst1[h1 * 32 + lr], a3d = adst1[h1 * 32 + 16 + lr];
    #pragma unroll
    for (int i = 0; i < 4; i++) {
      #pragma unroll
      for (int q = 0; q < 4; q++) {
        float s0 = acc[i][0][q] * a0s + acc[i][1][q] * a1s;
        float s1 = acc[i][2][q] * a2s + acc[i][3][q] * a3s;
        float d0 = acc[i][0][q] * a0d + acc[i][1][q] * a1d;
        float d1 = acc[i][2][q] * a2d + acc[i][3][q] * a3d;
        #pragma unroll
        for (int off = 1; off < 16; off <<= 1) {
          s0 += __shfl_xor(s0, off);
          s1 += __shfl_xor(s1, off);
          d0 += __shfl_xor(d0, off);
          d1 += __shfl_xor(d1, off);
        }
        int gr = row0 + wm * 64 + i * 16 + kg * 4 + q;
        if (lr == 0 && gr < N_NODES) {
          as1[gr * 8 + h0] = s0;
          as1[gr * 8 + h1] = s1;
          ad1[gr * 8 + h0] = d0;
          ad1[gr * 8 + h1] = d1;
        }
      }
    }
  }

  #pragma unroll
  for (int i = 0; i < 4; i++) {
    #pragma unroll
    for (int j = 0; j < 4; j++) {
      int gc = wn * 64 + j * 16 + lr;
      #pragma unroll
      for (int q = 0; q < 4; q++) {
        int gr = row0 + wm * 64 + i * 16 + kg * 4 + q;
        if (gr < N_NODES) Cb[(size_t)gr * HID + gc] = f2bf(acc[i][j][q]);
      }
    }
  }
}

// ---------------- GEMM2 + fused alpha2 ----------------
__global__ __launch_bounds__(256) void k_mm2(const ushort_t* __restrict__ At,
                                             const ushort_t* __restrict__ Bt,
                                             const float* __restrict__ asrc2,
                                             const float* __restrict__ adst2,
                                             ushort_t* __restrict__ Cb,
                                             float* __restrict__ as2,
                                             float* __restrict__ ad2) {
  __shared__ ushort_t sA[128][40];
  __shared__ ushort_t sB[64][40];
  int tid = threadIdx.x;
  int wid = tid >> 6, lane = tid & 63;
  int lr = lane & 15, kg = lane >> 4;
  int row0 = blockIdx.x * 128;
  f32x4 acc[2][4] = {};

  for (int kt = 0; kt < HID / 32; ++kt) {
    {
      const ushort_t* src = At + ((size_t)blockIdx.x * 8 + kt) * 4096 + tid * 16;
      uint4 v0 = *reinterpret_cast<const uint4*>(src);
      uint4 v1 = *reinterpret_cast<const uint4*>(src + 8);
      int r = tid >> 1, ks = (tid & 1) * 16;
      *reinterpret_cast<uint4*>(&sA[r][ks]) = v0;
      *reinterpret_cast<uint4*>(&sA[r][ks + 8]) = v1;
    }
    if (tid < 128) {
      int n = tid >> 1, ks = (tid & 1) * 16;
      const ushort_t* src = Bt + (size_t)n * HID + kt * 32 + ks;
      uint4 v0 = *reinterpret_cast<const uint4*>(src);
      uint4 v1 = *reinterpret_cast<const uint4*>(src + 8);
      *reinterpret_cast<uint4*>(&sB[n][ks]) = v0;
      *reinterpret_cast<uint4*>(&sB[n][ks + 8]) = v1;
    }
    __syncthreads();

    bf16x8 af[2], bfr[4];
    #pragma unroll
    for (int i = 0; i < 2; i++)
      af[i] = *reinterpret_cast<const bf16x8*>(&sA[wid * 32 + i * 16 + lr][kg * 8]);
    #pragma unroll
    for (int j = 0; j < 4; j++)
      bfr[j] = *reinterpret_cast<const bf16x8*>(&sB[j * 16 + lr][kg * 8]);
    #pragma unroll
    for (int i = 0; i < 2; i++)
      #pragma unroll
      for (int j = 0; j < 4; j++)
        acc[i][j] = __builtin_amdgcn_mfma_f32_16x16x32_bf16(af[i], bfr[j], acc[i][j], 0, 0, 0);
    __syncthreads();
  }

  // fused alpha2 from fp32 acc
  {
    float avs[4], avd[4];
    #pragma unroll
    for (int j = 0; j < 4; j++) {
      avs[j] = asrc2[j * 16 + lr];
      avd[j] = adst2[j * 16 + lr];
    }
    #pragma unroll
    for (int i = 0; i < 2; i++) {
      #pragma unroll
      for (int q = 0; q < 4; q++) {
        float s = acc[i][0][q] * avs[0] + acc[i][1][q] * avs[1]
                + acc[i][2][q] * avs[2] + acc[i][3][q] * avs[3];
        float d = acc[i][0][q] * avd[0] + acc[i][1][q] * avd[1]
                + acc[i][2][q] * avd[2] + acc[i][3][q] * avd[3];
        #pragma unroll
        for (int off = 1; off < 16; off <<= 1) {
          s += __shfl_xor(s, off);
          d += __shfl_xor(d, off);
        }
        int gr = row0 + wid * 32 + i * 16 + kg * 4 + q;
        if (lr == 0 && gr < N_NODES) { as2[gr] = s; ad2[gr] = d; }
      }
    }
  }

  #pragma unroll
  for (int i = 0; i < 2; i++) {
    #pragma unroll
    for (int j = 0; j < 4; j++) {
      int gc = j * 16 + lr;
      #pragma unroll
      for (int q = 0; q < 4; q++) {
        int gr = row0 + wid * 32 + i * 16 + kg * 4 + q;
        if (gr < N_NODES) Cb[(size_t)gr * OUT_C + gc] = f2bf(acc[i][j][q]);
      }
    }
  }
}

// ---------------- layer-1 aggregation: unroll-4 per half (measured floor) ----------------
__global__ __launch_bounds__(256) void k_agg1(const ushort_t* __restrict__ h1b,
                                              const int* __restrict__ indptr,
                                              const int* __restrict__ csr_src,
                                              const float* __restrict__ as1,
                                              const float* __restrict__ ad1,
                                              const float* __restrict__ b1,
                                              ushort_t* __restrict__ hpb) {
  int wave = threadIdx.x >> 6, lane = threadIdx.x & 63;
  int node = blockIdx.x * 4 + wave;
  if (node >= N_NODES) return;
  int beg = indptr[node], end = indptr[node + 1];
  int half = lane >> 5, sl = lane & 31, h = sl >> 2;   // lane sl covers cols sl*8..sl*8+7
  float adst = ad1[node * 8 + h];

  f32x2 a0 = {0.f, 0.f}, a1 = {0.f, 0.f}, a2 = {0.f, 0.f}, a3 = {0.f, 0.f};
  float dsum = 0.f;
  int e = beg + half;
  for (; e + 6 < end; e += 8) {        // 4 edges per iter in this half's stride
    int s0 = csr_src[e];
    int s1 = csr_src[e + 2];
    int s2 = csr_src[e + 4];
    int s3 = csr_src[e + 6];
    float l0 = as1[s0 * 8 + h];
    float l1 = as1[s1 * 8 + h];
    float l2 = as1[s2 * 8 + h];
    float l3 = as1[s3 * 8 + h];
    uint4 r0 = *reinterpret_cast<const uint4*>(&h1b[(size_t)s0 * HID + sl * 8]);
    uint4 r1 = *reinterpret_cast<const uint4*>(&h1b[(size_t)s1 * HID + sl * 8]);
    uint4 r2 = *reinterpret_cast<const uint4*>(&h1b[(size_t)s2 * HID + sl * 8]);
    uint4 r3 = *reinterpret_cast<const uint4*>(&h1b[(size_t)s3 * HID + sl * 8]);
    float w0 = __expf(lrelu(l0 + adst));
    float w1 = __expf(lrelu(l1 + adst));
    float w2 = __expf(lrelu(l2 + adst));
    float w3 = __expf(lrelu(l3 + adst));
    a0 += w0 * unp2(r0.x); a1 += w0 * unp2(r0.y); a2 += w0 * unp2(r0.z); a3 += w0 * unp2(r0.w);
    a0 += w1 * unp2(r1.x); a1 += w1 * unp2(r1.y); a2 += w1 * unp2(r1.z); a3 += w1 * unp2(r1.w);
    a0 += w2 * unp2(r2.x); a1 += w2 * unp2(r2.y); a2 += w2 * unp2(r2.z); a3 += w2 * unp2(r2.w);
    a0 += w3 * unp2(r3.x); a1 += w3 * unp2(r3.y); a2 += w3 * unp2(r3.z); a3 += w3 * unp2(r3.w);
    dsum += w0 + w1 + w2 + w3;
  }
  for (; e < end; e += 2) {
    int s = csr_src[e];
    float w = __expf(lrelu(as1[s * 8 + h] + adst));
    uint4 rv = *reinterpret_cast<const uint4*>(&h1b[(size_t)s * HID + sl * 8]);
    a0 += w * unp2(rv.x); a1 += w * unp2(rv.y); a2 += w * unp2(rv.z); a3 += w * unp2(rv.w);
    dsum += w;
  }
  float acc[8] = {a0.x, a0.y, a1.x, a1.y, a2.x, a2.y, a3.x, a3.y};
  #pragma unroll
  for (int j = 0; j < 8; j++) acc[j] += __shfl_xor(acc[j], 32);
  dsum += __shfl_xor(dsum, 32);
  float inv = 1.f / (dsum + 1e-16f);

  if (half == 0) {
    unsigned short ob[8];
    #pragma unroll
    for (int j = 0; j < 8; j++) {
      float o = acc[j] * inv + b1[sl * 8 + j];
      o = o > 0.f ? o : expm1f(o);
      ob[j] = f2bf(o);
    }
    uint4 pk;
    pk.x = ob[0] | ((uint)ob[1] << 16); pk.y = ob[2] | ((uint)ob[3] << 16);
    pk.z = ob[4] | ((uint)ob[5] << 16); pk.w = ob[6] | ((uint)ob[7] << 16);
    size_t addr = ((size_t)(node >> 7) * 8 + (sl >> 2)) * 4096 + (size_t)(node & 127) * 32 + (sl & 3) * 8;
    *reinterpret_cast<uint4*>(&hpb[addr]) = pk;
  }
}

// ---------------- layer-2 aggregation: bf16 gather, unroll-4 ----------------
__global__ __launch_bounds__(256) void k_agg2(const ushort_t* __restrict__ h2b,
                                              const int* __restrict__ indptr,
                                              const int* __restrict__ csr_src,
                                              const float* __restrict__ as2,
                                              const float* __restrict__ ad2,
                                              const float* __restrict__ b2,
                                              float* __restrict__ out) {
  int wave = threadIdx.x >> 6, lane = threadIdx.x & 63;
  int node = blockIdx.x * 4 + wave;
  if (node >= N_NODES) return;
  int beg = indptr[node], end = indptr[node + 1];
  int half = lane >> 5, sl = lane & 31;   // lane sl covers ch 2sl, 2sl+1 (4B bf16x2)
  float adst = ad2[node];

  f32x2 acc2 = {0.f, 0.f};
  float dsum = 0.f;
  int e = beg + half;
  for (; e + 6 < end; e += 8) {
    int s0 = csr_src[e];
    int s1 = csr_src[e + 2];
    int s2 = csr_src[e + 4];
    int s3 = csr_src[e + 6];
    float l0 = as2[s0];
    float l1 = as2[s1];
    float l2 = as2[s2];
    float l3 = as2[s3];
    uint v0 = *reinterpret_cast<const uint*>(&h2b[(size_t)s0 * OUT_C + sl * 2]);
    uint v1 = *reinterpret_cast<const uint*>(&h2b[(size_t)s1 * OUT_C + sl * 2]);
    uint v2 = *reinterpret_cast<const uint*>(&h2b[(size_t)s2 * OUT_C + sl * 2]);
    uint v3 = *reinterpret_cast<const uint*>(&h2b[(size_t)s3 * OUT_C + sl * 2]);
    float w0 = __expf(lrelu(l0 + adst));
    float w1 = __expf(lrelu(l1 + adst));
    float w2 = __expf(lrelu(l2 + adst));
    float w3 = __expf(lrelu(l3 + adst));
    acc2 += w0 * unp2(v0); acc2 += w1 * unp2(v1);
    acc2 += w2 * unp2(v2); acc2 += w3 * unp2(v3);
    dsum += w0 + w1 + w2 + w3;
  }
  for (; e < end; e += 2) {
    int s = csr_src[e];
    float w = __expf(lrelu(as2[s] + adst));
    uint v = *reinterpret_cast<const uint*>(&h2b[(size_t)s * OUT_C + sl * 2]);
    acc2 += w * unp2(v);
    dsum += w;
  }
  acc2.x += __shfl_xor(acc2.x, 32);
  acc2.y += __shfl_xor(acc2.y, 32);
  dsum += __shfl_xor(dsum, 32);
  float inv = 1.f / (dsum + 1e-16f);
  if (half == 0) {
    float2 o = {acc2.x * inv + b2[sl * 2], acc2.y * inv + b2[sl * 2 + 1]};
    *reinterpret_cast<float2*>(&out[(size_t)node * OUT_C + sl * 2]) = o;
  }
}

extern "C" void kernel_launch(void* const* d_in, const int* in_sizes, int n_in,
                              void* d_out, int out_size, void* d_ws, size_t ws_size,
                              hipStream_t stream) {
  const float* x     = (const float*)d_in[0];
  const int*   ei    = (const int*)d_in[1];
  const float* W1    = (const float*)d_in[2];
  const float* asrc1 = (const float*)d_in[3];
  const float* adst1 = (const float*)d_in[4];
  const float* b1    = (const float*)d_in[5];
  const float* W2    = (const float*)d_in[6];
  const float* asrc2 = (const float*)d_in[7];
  const float* adst2 = (const float*)d_in[8];
  const float* b2    = (const float*)d_in[9];
  float* out = (float*)d_out;

  char* p = (char*)d_ws;
  size_t off = 0;
  auto take = [&](size_t bytes) -> void* {
    void* r = p + off;
    off += (bytes + 255) & ~(size_t)255;
    return r;
  };
  ushort_t* h1b  = (ushort_t*)take((size_t)N_NODES * HID * 2);
  ushort_t* hpb  = (ushort_t*)take((size_t)(M_PAD / 128) * 8 * 4096 * 2);
  ushort_t* h2b  = (ushort_t*)take((size_t)N_NODES * OUT_C * 2);
  float*    as1  = (float*)take((size_t)N_NODES * HEADS * 4);
  float*    ad1  = (float*)take((size_t)N_NODES * HEADS * 4);
  float*    as2  = (float*)take((size_t)N_NODES * 4);
  float*    ad2  = (float*)take((size_t)N_NODES * 4);
  int* counts = (int*)take((size_t)N_NODES * 4);
  int* indptr = (int*)take((size_t)(N_NODES + 1) * 4);
  int* wptr   = (int*)take((size_t)(N_NODES + 1) * 4);
  int* bsum   = (int*)take((size_t)NBLK * 4);
  int* boff   = (int*)take((size_t)NBLK * 4);
  int* csr    = (int*)take((size_t)E_TOT * 4);
  ushort_t* w1t = (ushort_t*)take((size_t)IN_C * HID * 2);
  ushort_t* w2t = (ushort_t*)take((size_t)HID * OUT_C * 2);

  // CSR count || weight transpose (independent work, one launch)
  hipMemsetAsync(counts, 0, (size_t)N_NODES * 4, stream);
  k_fatA<<<CNT_BLOCKS + CONVW_BLOCKS, 512, 0, stream>>>(ei, counts, W1, W2, w1t, w2t);
  k_bsum<<<NBLK, 256, 0, stream>>>(counts, bsum);
  k_bscan<<<1, 256, 0, stream>>>(bsum, boff);
  k_local<<<NBLK, 256, 0, stream>>>(counts, boff, indptr, wptr);

  // GEMM1+alpha1 || scatter (independent, one launch)
  k_fatB<<<MM1_BLOCKS + SCAT_BLOCKS, 512, 0, stream>>>(x, w1t, asrc1, adst1, h1b, as1, ad1,
                                                       ei, wptr, csr);

  k_agg1<<<(N_NODES + 3) / 4, 256, 0, stream>>>(h1b, indptr, csr, as1, ad1, b1, hpb);

  // layer 2
  k_mm2<<<M_PAD / 128, 256, 0, stream>>>(hpb, w2t, asrc2, adst2, h2b, as2, ad2);
  k_agg2<<<(N_NODES + 3) / 4, 256, 0, stream>>>(h2b, indptr, csr, as2, ad2, b2, out);
}

// Round 16
// 238.632 us; speedup vs baseline: 2.0922x; 1.0091x over previous
//
#include <hip/hip_runtime.h>

#define N_NODES 50000
#define M_PAD   50048            // 391 * 128
#define NBLK    196              // ceil(N_NODES/256)
#define E_EDGES 800000
#define E_TOT   (E_EDGES + N_NODES)
#define IN_C 512
#define HID 256
#define HEADS 8
#define OUT_C 64

#define MM1_BX 391
#define MM1_BLK (MM1_BX * 2)                     // 782 (column-split)
#define SCAT_BLOCKS ((E_TOT + 255) / 256)        // 3321 (256-thread)
#define CNT_BLOCKS  ((E_TOT + 511) / 512)        // 1661
#define CONVW_ELEMS (HID * IN_C + OUT_C * HID)   // 147456
#define CONVW_BLOCKS ((CONVW_ELEMS + 511) / 512) // 288

typedef unsigned int uint;
typedef unsigned short ushort_t;
typedef __bf16 bf16x8 __attribute__((ext_vector_type(8)));
typedef float f32x4 __attribute__((ext_vector_type(4)));
typedef float f32x2 __attribute__((ext_vector_type(2)));

__device__ __forceinline__ float lrelu(float x) { return x > 0.f ? x : 0.2f * x; }

__device__ __forceinline__ unsigned short f2bf(float f) {
  __bf16 b = (__bf16)f;                       // compiler RNE cvt
  return __builtin_bit_cast(unsigned short, b);
}
__device__ __forceinline__ float bflo(uint u) { return __uint_as_float(u << 16); }
__device__ __forceinline__ float bfhi(uint u) { return __uint_as_float(u & 0xFFFF0000u); }
__device__ __forceinline__ f32x2 unp2(uint u) {
  f32x2 r; r.x = bflo(u); r.y = bfhi(u); return r;
}

// ---------------- fatA: edge-count || weight transpose ----------------
__global__ __launch_bounds__(512) void k_fatA(const int* __restrict__ ei,
                                              int* __restrict__ counts,
                                              const float* __restrict__ W1,
                                              const float* __restrict__ W2,
                                              ushort_t* __restrict__ w1t,
                                              ushort_t* __restrict__ w2t) {
  int bid = blockIdx.x;
  if (bid < CNT_BLOCKS) {
    int e = bid * 512 + threadIdx.x;
    if (e >= E_TOT) return;
    int d = (e < E_EDGES) ? ei[E_EDGES + e] : (e - E_EDGES);
    atomicAdd(&counts[d], 1);
  } else {
    int t = (bid - CNT_BLOCKS) * 512 + threadIdx.x;
    if (t < HID * IN_C) {
      int n = t >> 9, k = t & 511;
      w1t[t] = f2bf(W1[(size_t)k * HID + n]);
    } else if (t < CONVW_ELEMS) {
      int u = t - HID * IN_C;
      int n = u >> 8, k = u & 255;
      w2t[u] = f2bf(W2[(size_t)k * OUT_C + n]);
    }
  }
}

// ---------------- scan kernels ----------------
__global__ void k_bsum(const int* __restrict__ counts, int* __restrict__ bsum) {
  int i = blockIdx.x * 256 + threadIdx.x;
  int v = (i < N_NODES) ? counts[i] : 0;
  __shared__ int ws[4];
  int lane = threadIdx.x & 63, wid = threadIdx.x >> 6;
  #pragma unroll
  for (int off = 32; off; off >>= 1) v += __shfl_xor(v, off);
  if (lane == 0) ws[wid] = v;
  __syncthreads();
  if (threadIdx.x == 0) bsum[blockIdx.x] = ws[0] + ws[1] + ws[2] + ws[3];
}

__global__ void k_bscan(const int* __restrict__ bsum, int* __restrict__ boff) {
  int tid = threadIdx.x;
  int v = (tid < NBLK) ? bsum[tid] : 0;
  int lane = tid & 63, wid = tid >> 6;
  int x = v;
  #pragma unroll
  for (int off = 1; off < 64; off <<= 1) {
    int t = __shfl_up(x, off);
    if (lane >= off) x += t;
  }
  __shared__ int ws[4];
  if (lane == 63) ws[wid] = x;
  __syncthreads();
  int woff = 0;
  for (int w = 0; w < wid; w++) woff += ws[w];
  if (tid < NBLK) boff[tid] = x + woff - v;   // exclusive
}

__global__ void k_local(const int* __restrict__ counts, const int* __restrict__ boff,
                        int* __restrict__ indptr, int* __restrict__ wptr) {
  int b = blockIdx.x;
  int i = b * 256 + threadIdx.x;
  int v = (i < N_NODES) ? counts[i] : 0;
  int lane = threadIdx.x & 63, wid = threadIdx.x >> 6;
  int x = v;
  #pragma unroll
  for (int off = 1; off < 64; off <<= 1) {
    int t = __shfl_up(x, off);
    if (lane >= off) x += t;
  }
  __shared__ int ws[4];
  if (lane == 63) ws[wid] = x;
  __syncthreads();
  int woff = boff[b];
  for (int w = 0; w < wid; w++) woff += ws[w];
  int excl = woff + x - v;
  if (i < N_NODES) { indptr[i] = excl; wptr[i] = excl; }
  if (b == 0 && threadIdx.x == 0) indptr[N_NODES] = E_TOT;
}

// ---------------- fatB: GEMM1(128x128 tiles, 782 blocks)+alpha1 || scatter ----------------
__global__ __launch_bounds__(256) void k_fatB(const float* __restrict__ A,
                                              const ushort_t* __restrict__ Bt,
                                              const float* __restrict__ asrc1,
                                              const float* __restrict__ adst1,
                                              ushort_t* __restrict__ Cb,
                                              float* __restrict__ as1,
                                              float* __restrict__ ad1,
                                              const int* __restrict__ ei,
                                              int* __restrict__ wptr,
                                              int* __restrict__ csr_src) {
  if (blockIdx.x >= MM1_BLK) {
    // ---- scatter part ----
    int e = (blockIdx.x - MM1_BLK) * 256 + threadIdx.x;
    if (e >= E_TOT) return;
    int s, d;
    if (e < E_EDGES) { s = ei[e]; d = ei[E_EDGES + e]; }
    else { s = d = e - E_EDGES; }
    int pos = atomicAdd(&wptr[d], 1);
    csr_src[pos] = s;
    return;
  }
  // ---- mm1 part: 128x128 tile, 4 waves (2x2), 64x64 per wave ----
  int bx = blockIdx.x >> 1, by = blockIdx.x & 1;
  __shared__ ushort_t sA[128][40];
  __shared__ ushort_t sB[128][40];
  int tid = threadIdx.x;
  int wid = tid >> 6, lane = tid & 63;
  int wm = wid >> 1, wn = wid & 1;
  int lr = lane & 15, kg = lane >> 4;
  int row0 = bx * 128;
  int cb0 = by * 128;
  f32x4 acc[4][4] = {};

  for (int k0 = 0; k0 < IN_C; k0 += 32) {
    {  // stage A: 128x32 fp32->bf16; 2 threads/row, 16 floats each
      int r = tid >> 1, cs = (tid & 1) * 16;
      int gr = row0 + r;
      unsigned short v[16];
      if (gr < N_NODES) {
        const float* src = A + (size_t)gr * IN_C + k0 + cs;
        #pragma unroll
        for (int i = 0; i < 4; i++) {
          float4 f = *reinterpret_cast<const float4*>(src + i * 4);
          v[i * 4 + 0] = f2bf(f.x); v[i * 4 + 1] = f2bf(f.y);
          v[i * 4 + 2] = f2bf(f.z); v[i * 4 + 3] = f2bf(f.w);
        }
      } else {
        #pragma unroll
        for (int i = 0; i < 16; i++) v[i] = 0;
      }
      uint4 p0, p1;
      p0.x = v[0] | ((uint)v[1] << 16);  p0.y = v[2] | ((uint)v[3] << 16);
      p0.z = v[4] | ((uint)v[5] << 16);  p0.w = v[6] | ((uint)v[7] << 16);
      p1.x = v[8] | ((uint)v[9] << 16);  p1.y = v[10] | ((uint)v[11] << 16);
      p1.z = v[12] | ((uint)v[13] << 16); p1.w = v[14] | ((uint)v[15] << 16);
      *reinterpret_cast<uint4*>(&sA[r][cs]) = p0;
      *reinterpret_cast<uint4*>(&sA[r][cs + 8]) = p1;
    }
    {  // stage B: rows cb0..cb0+127 of w1t; 2 threads/row, 16 bf16 each
      int n = tid >> 1, ks = (tid & 1) * 16;
      const ushort_t* src = Bt + (size_t)(cb0 + n) * IN_C + k0 + ks;
      uint4 v0 = *reinterpret_cast<const uint4*>(src);
      uint4 v1 = *reinterpret_cast<const uint4*>(src + 8);
      *reinterpret_cast<uint4*>(&sB[n][ks]) = v0;
      *reinterpret_cast<uint4*>(&sB[n][ks + 8]) = v1;
    }
    __syncthreads();

    bf16x8 af[4], bfr[4];
    #pragma unroll
    for (int i = 0; i < 4; i++)
      af[i] = *reinterpret_cast<const bf16x8*>(&sA[wm * 64 + i * 16 + lr][kg * 8]);
    #pragma unroll
    for (int j = 0; j < 4; j++)
      bfr[j] = *reinterpret_cast<const bf16x8*>(&sB[wn * 64 + j * 16 + lr][kg * 8]);
    #pragma unroll
    for (int i = 0; i < 4; i++)
      #pragma unroll
      for (int j = 0; j < 4; j++)
        acc[i][j] = __builtin_amdgcn_mfma_f32_16x16x32_bf16(af[i], bfr[j], acc[i][j], 0, 0, 0);
    __syncthreads();
  }

  // fused alpha1: this wave covers heads h0, h0+1 (64 cols)
  {
    int h0 = by * 4 + wn * 2, h1 = h0 + 1;
    float a0s = asrc1[h0 * 32 + lr], a1s = asrc1[h0 * 32 + 16 + lr];
    float a2s = asrc1[h1 * 32 + lr], a3s = asrc1[h1 * 32 + 16 + lr];
    float a0d = adst1[h0 * 32 + lr], a1d = adst1[h0 * 32 + 16 + lr];
    float a2d = adst1[h1 * 32 + lr], a3d = adst1[h1 * 32 + 16 + lr];
    #pragma unroll
    for (int i = 0; i < 4; i++) {
      #pragma unroll
      for (int q = 0; q < 4; q++) {
        float s0 = acc[i][0][q] * a0s + acc[i][1][q] * a1s;
        float s1 = acc[i][2][q] * a2s + acc[i][3][q] * a3s;
        float d0 = acc[i][0][q] * a0d + acc[i][1][q] * a1d;
        float d1 = acc[i][2][q] * a2d + acc[i][3][q] * a3d;
        #pragma unroll
        for (int off = 1; off < 16; off <<= 1) {
          s0 += __shfl_xor(s0, off);
          s1 += __shfl_xor(s1, off);
          d0 += __shfl_xor(d0, off);
          d1 += __shfl_xor(d1, off);
        }
        int gr = row0 + wm * 64 + i * 16 + kg * 4 + q;
        if (lr == 0 && gr < N_NODES) {
          as1[gr * 8 + h0] = s0;
          as1[gr * 8 + h1] = s1;
          ad1[gr * 8 + h0] = d0;
          ad1[gr * 8 + h1] = d1;
        }
      }
    }
  }

  #pragma unroll
  for (int i = 0; i < 4; i++) {
    #pragma unroll
    for (int j = 0; j < 4; j++) {
      int gc = cb0 + wn * 64 + j * 16 + lr;
      #pragma unroll
      for (int q = 0; q < 4; q++) {
        int gr = row0 + wm * 64 + i * 16 + kg * 4 + q;
        if (gr < N_NODES) Cb[(size_t)gr * HID + gc] = f2bf(acc[i][j][q]);
      }
    }
  }
}

// ---------------- GEMM2 + fused alpha2 ----------------
__global__ __launch_bounds__(256) void k_mm2(const ushort_t* __restrict__ At,
                                             const ushort_t* __restrict__ Bt,
                                             const float* __restrict__ asrc2,
                                             const float* __restrict__ adst2,
                                             ushort_t* __restrict__ Cb,
                                             float* __restrict__ as2,
                                             float* __restrict__ ad2) {
  __shared__ ushort_t sA[128][40];
  __shared__ ushort_t sB[64][40];
  int tid = threadIdx.x;
  int wid = tid >> 6, lane = tid & 63;
  int lr = lane & 15, kg = lane >> 4;
  int row0 = blockIdx.x * 128;
  f32x4 acc[2][4] = {};

  for (int kt = 0; kt < HID / 32; ++kt) {
    {
      const ushort_t* src = At + ((size_t)blockIdx.x * 8 + kt) * 4096 + tid * 16;
      uint4 v0 = *reinterpret_cast<const uint4*>(src);
      uint4 v1 = *reinterpret_cast<const uint4*>(src + 8);
      int r = tid >> 1, ks = (tid & 1) * 16;
      *reinterpret_cast<uint4*>(&sA[r][ks]) = v0;
      *reinterpret_cast<uint4*>(&sA[r][ks + 8]) = v1;
    }
    if (tid < 128) {
      int n = tid >> 1, ks = (tid & 1) * 16;
      const ushort_t* src = Bt + (size_t)n * HID + kt * 32 + ks;
      uint4 v0 = *reinterpret_cast<const uint4*>(src);
      uint4 v1 = *reinterpret_cast<const uint4*>(src + 8);
      *reinterpret_cast<uint4*>(&sB[n][ks]) = v0;
      *reinterpret_cast<uint4*>(&sB[n][ks + 8]) = v1;
    }
    __syncthreads();

    bf16x8 af[2], bfr[4];
    #pragma unroll
    for (int i = 0; i < 2; i++)
      af[i] = *reinterpret_cast<const bf16x8*>(&sA[wid * 32 + i * 16 + lr][kg * 8]);
    #pragma unroll
    for (int j = 0; j < 4; j++)
      bfr[j] = *reinterpret_cast<const bf16x8*>(&sB[j * 16 + lr][kg * 8]);
    #pragma unroll
    for (int i = 0; i < 2; i++)
      #pragma unroll
      for (int j = 0; j < 4; j++)
        acc[i][j] = __builtin_amdgcn_mfma_f32_16x16x32_bf16(af[i], bfr[j], acc[i][j], 0, 0, 0);
    __syncthreads();
  }

  // fused alpha2 from fp32 acc
  {
    float avs[4], avd[4];
    #pragma unroll
    for (int j = 0; j < 4; j++) {
      avs[j] = asrc2[j * 16 + lr];
      avd[j] = adst2[j * 16 + lr];
    }
    #pragma unroll
    for (int i = 0; i < 2; i++) {
      #pragma unroll
      for (int q = 0; q < 4; q++) {
        float s = acc[i][0][q] * avs[0] + acc[i][1][q] * avs[1]
                + acc[i][2][q] * avs[2] + acc[i][3][q] * avs[3];
        float d = acc[i][0][q] * avd[0] + acc[i][1][q] * avd[1]
                + acc[i][2][q] * avd[2] + acc[i][3][q] * avd[3];
        #pragma unroll
        for (int off = 1; off < 16; off <<= 1) {
          s += __shfl_xor(s, off);
          d += __shfl_xor(d, off);
        }
        int gr = row0 + wid * 32 + i * 16 + kg * 4 + q;
        if (lr == 0 && gr < N_NODES) { as2[gr] = s; ad2[gr] = d; }
      }
    }
  }

  #pragma unroll
  for (int i = 0; i < 2; i++) {
    #pragma unroll
    for (int j = 0; j < 4; j++) {
      int gc = j * 16 + lr;
      #pragma unroll
      for (int q = 0; q < 4; q++) {
        int gr = row0 + wid * 32 + i * 16 + kg * 4 + q;
        if (gr < N_NODES) Cb[(size_t)gr * OUT_C + gc] = f2bf(acc[i][j][q]);
      }
    }
  }
}

// ---------------- layer-1 aggregation: unroll-4 per half (measured floor) ----------------
__global__ __launch_bounds__(256) void k_agg1(const ushort_t* __restrict__ h1b,
                                              const int* __restrict__ indptr,
                                              const int* __restrict__ csr_src,
                                              const float* __restrict__ as1,
                                              const float* __restrict__ ad1,
                                              const float* __restrict__ b1,
                                              ushort_t* __restrict__ hpb) {
  int wave = threadIdx.x >> 6, lane = threadIdx.x & 63;
  int node = blockIdx.x * 4 + wave;
  if (node >= N_NODES) return;
  int beg = indptr[node], end = indptr[node + 1];
  int half = lane >> 5, sl = lane & 31, h = sl >> 2;   // lane sl covers cols sl*8..sl*8+7
  float adst = ad1[node * 8 + h];

  f32x2 a0 = {0.f, 0.f}, a1 = {0.f, 0.f}, a2 = {0.f, 0.f}, a3 = {0.f, 0.f};
  float dsum = 0.f;
  int e = beg + half;
  for (; e + 6 < end; e += 8) {        // 4 edges per iter in this half's stride
    int s0 = csr_src[e];
    int s1 = csr_src[e + 2];
    int s2 = csr_src[e + 4];
    int s3 = csr_src[e + 6];
    float l0 = as1[s0 * 8 + h];
    float l1 = as1[s1 * 8 + h];
    float l2 = as1[s2 * 8 + h];
    float l3 = as1[s3 * 8 + h];
    uint4 r0 = *reinterpret_cast<const uint4*>(&h1b[(size_t)s0 * HID + sl * 8]);
    uint4 r1 = *reinterpret_cast<const uint4*>(&h1b[(size_t)s1 * HID + sl * 8]);
    uint4 r2 = *reinterpret_cast<const uint4*>(&h1b[(size_t)s2 * HID + sl * 8]);
    uint4 r3 = *reinterpret_cast<const uint4*>(&h1b[(size_t)s3 * HID + sl * 8]);
    float w0 = __expf(lrelu(l0 + adst));
    float w1 = __expf(lrelu(l1 + adst));
    float w2 = __expf(lrelu(l2 + adst));
    float w3 = __expf(lrelu(l3 + adst));
    a0 += w0 * unp2(r0.x); a1 += w0 * unp2(r0.y); a2 += w0 * unp2(r0.z); a3 += w0 * unp2(r0.w);
    a0 += w1 * unp2(r1.x); a1 += w1 * unp2(r1.y); a2 += w1 * unp2(r1.z); a3 += w1 * unp2(r1.w);
    a0 += w2 * unp2(r2.x); a1 += w2 * unp2(r2.y); a2 += w2 * unp2(r2.z); a3 += w2 * unp2(r2.w);
    a0 += w3 * unp2(r3.x); a1 += w3 * unp2(r3.y); a2 += w3 * unp2(r3.z); a3 += w3 * unp2(r3.w);
    dsum += w0 + w1 + w2 + w3;
  }
  for (; e < end; e += 2) {
    int s = csr_src[e];
    float w = __expf(lrelu(as1[s * 8 + h] + adst));
    uint4 rv = *reinterpret_cast<const uint4*>(&h1b[(size_t)s * HID + sl * 8]);
    a0 += w * unp2(rv.x); a1 += w * unp2(rv.y); a2 += w * unp2(rv.z); a3 += w * unp2(rv.w);
    dsum += w;
  }
  float acc[8] = {a0.x, a0.y, a1.x, a1.y, a2.x, a2.y, a3.x, a3.y};
  #pragma unroll
  for (int j = 0; j < 8; j++) acc[j] += __shfl_xor(acc[j], 32);
  dsum += __shfl_xor(dsum, 32);
  float inv = 1.f / (dsum + 1e-16f);

  if (half == 0) {
    unsigned short ob[8];
    #pragma unroll
    for (int j = 0; j < 8; j++) {
      float o = acc[j] * inv + b1[sl * 8 + j];
      o = o > 0.f ? o : expm1f(o);
      ob[j] = f2bf(o);
    }
    uint4 pk;
    pk.x = ob[0] | ((uint)ob[1] << 16); pk.y = ob[2] | ((uint)ob[3] << 16);
    pk.z = ob[4] | ((uint)ob[5] << 16); pk.w = ob[6] | ((uint)ob[7] << 16);
    size_t addr = ((size_t)(node >> 7) * 8 + (sl >> 2)) * 4096 + (size_t)(node & 127) * 32 + (sl & 3) * 8;
    *reinterpret_cast<uint4*>(&hpb[addr]) = pk;
  }
}

// ---------------- layer-2 aggregation: bf16 gather, unroll-4 ----------------
__global__ __launch_bounds__(256) void k_agg2(const ushort_t* __restrict__ h2b,
                                              const int* __restrict__ indptr,
                                              const int* __restrict__ csr_src,
                                              const float* __restrict__ as2,
                                              const float* __restrict__ ad2,
                                              const float* __restrict__ b2,
                                              float* __restrict__ out) {
  int wave = threadIdx.x >> 6, lane = threadIdx.x & 63;
  int node = blockIdx.x * 4 + wave;
  if (node >= N_NODES) return;
  int beg = indptr[node], end = indptr[node + 1];
  int half = lane >> 5, sl = lane & 31;   // lane sl covers ch 2sl, 2sl+1 (4B bf16x2)
  float adst = ad2[node];

  f32x2 acc2 = {0.f, 0.f};
  float dsum = 0.f;
  int e = beg + half;
  for (; e + 6 < end; e += 8) {
    int s0 = csr_src[e];
    int s1 = csr_src[e + 2];
    int s2 = csr_src[e + 4];
    int s3 = csr_src[e + 6];
    float l0 = as2[s0];
    float l1 = as2[s1];
    float l2 = as2[s2];
    float l3 = as2[s3];
    uint v0 = *reinterpret_cast<const uint*>(&h2b[(size_t)s0 * OUT_C + sl * 2]);
    uint v1 = *reinterpret_cast<const uint*>(&h2b[(size_t)s1 * OUT_C + sl * 2]);
    uint v2 = *reinterpret_cast<const uint*>(&h2b[(size_t)s2 * OUT_C + sl * 2]);
    uint v3 = *reinterpret_cast<const uint*>(&h2b[(size_t)s3 * OUT_C + sl * 2]);
    float w0 = __expf(lrelu(l0 + adst));
    float w1 = __expf(lrelu(l1 + adst));
    float w2 = __expf(lrelu(l2 + adst));
    float w3 = __expf(lrelu(l3 + adst));
    acc2 += w0 * unp2(v0); acc2 += w1 * unp2(v1);
    acc2 += w2 * unp2(v2); acc2 += w3 * unp2(v3);
    dsum += w0 + w1 + w2 + w3;
  }
  for (; e < end; e += 2) {
    int s = csr_src[e];
    float w = __expf(lrelu(as2[s] + adst));
    uint v = *reinterpret_cast<const uint*>(&h2b[(size_t)s * OUT_C + sl * 2]);
    acc2 += w * unp2(v);
    dsum += w;
  }
  acc2.x += __shfl_xor(acc2.x, 32);
  acc2.y += __shfl_xor(acc2.y, 32);
  dsum += __shfl_xor(dsum, 32);
  float inv = 1.f / (dsum + 1e-16f);
  if (half == 0) {
    float2 o = {acc2.x * inv + b2[sl * 2], acc2.y * inv + b2[sl * 2 + 1]};
    *reinterpret_cast<float2*>(&out[(size_t)node * OUT_C + sl * 2]) = o;
  }
}

extern "C" void kernel_launch(void* const* d_in, const int* in_sizes, int n_in,
                              void* d_out, int out_size, void* d_ws, size_t ws_size,
                              hipStream_t stream) {
  const float* x     = (const float*)d_in[0];
  const int*   ei    = (const int*)d_in[1];
  const float* W1    = (const float*)d_in[2];
  const float* asrc1 = (const float*)d_in[3];
  const float* adst1 = (const float*)d_in[4];
  const float* b1    = (const float*)d_in[5];
  const float* W2    = (const float*)d_in[6];
  const float* asrc2 = (const float*)d_in[7];
  const float* adst2 = (const float*)d_in[8];
  const float* b2    = (const float*)d_in[9];
  float* out = (float*)d_out;

  char* p = (char*)d_ws;
  size_t off = 0;
  auto take = [&](size_t bytes) -> void* {
    void* r = p + off;
    off += (bytes + 255) & ~(size_t)255;
    return r;
  };
  ushort_t* h1b  = (ushort_t*)take((size_t)N_NODES * HID * 2);
  ushort_t* hpb  = (ushort_t*)take((size_t)(M_PAD / 128) * 8 * 4096 * 2);
  ushort_t* h2b  = (ushort_t*)take((size_t)N_NODES * OUT_C * 2);
  float*    as1  = (float*)take((size_t)N_NODES * HEADS * 4);
  float*    ad1  = (float*)take((size_t)N_NODES * HEADS * 4);
  float*    as2  = (float*)take((size_t)N_NODES * 4);
  float*    ad2  = (float*)take((size_t)N_NODES * 4);
  int* counts = (int*)take((size_t)N_NODES * 4);
  int* indptr = (int*)take((size_t)(N_NODES + 1) * 4);
  int* wptr   = (int*)take((size_t)(N_NODES + 1) * 4);
  int* bsum   = (int*)take((size_t)NBLK * 4);
  int* boff   = (int*)take((size_t)NBLK * 4);
  int* csr    = (int*)take((size_t)E_TOT * 4);
  ushort_t* w1t = (ushort_t*)take((size_t)IN_C * HID * 2);
  ushort_t* w2t = (ushort_t*)take((size_t)HID * OUT_C * 2);

  // CSR count || weight transpose (independent work, one launch)
  hipMemsetAsync(counts, 0, (size_t)N_NODES * 4, stream);
  k_fatA<<<CNT_BLOCKS + CONVW_BLOCKS, 512, 0, stream>>>(ei, counts, W1, W2, w1t, w2t);
  k_bsum<<<NBLK, 256, 0, stream>>>(counts, bsum);
  k_bscan<<<1, 256, 0, stream>>>(bsum, boff);
  k_local<<<NBLK, 256, 0, stream>>>(counts, boff, indptr, wptr);

  // GEMM1+alpha1 (column-split, 782 blocks) || scatter (one launch)
  k_fatB<<<MM1_BLK + SCAT_BLOCKS, 256, 0, stream>>>(x, w1t, asrc1, adst1, h1b, as1, ad1,
                                                    ei, wptr, csr);

  k_agg1<<<(N_NODES + 3) / 4, 256, 0, stream>>>(h1b, indptr, csr, as1, ad1, b1, hpb);

  // layer 2
  k_mm2<<<M_PAD / 128, 256, 0, stream>>>(hpb, w2t, asrc2, adst2, h2b, as2, ad2);
  k_agg2<<<(N_NODES + 3) / 4, 256, 0, stream>>>(h2b, indptr, csr, as2, ad2, b2, out);
}